// Round 1
// baseline (3396.487 us; speedup 1.0000x reference)
//
#include <hip/hip_runtime.h>

#define N_NODES 100000
#define N_EDGES 640000
#define LATDIM  128
#define LN_EPS  1e-5f

// One wave (64 lanes) per row; 4 rows per 256-thread block.
__global__ __launch_bounds__(256) void ln_kernel(const float* __restrict__ in,
                                                 float* __restrict__ out) {
    int row = blockIdx.x * 4 + (threadIdx.x >> 6);
    if (row >= N_NODES) return;
    int lane = threadIdx.x & 63;
    const float2* ip = (const float2*)(in + (size_t)row * LATDIM);
    float2 v = ip[lane];
    float s  = v.x + v.y;
    float ss = v.x * v.x + v.y * v.y;
    #pragma unroll
    for (int o = 32; o > 0; o >>= 1) {
        s  += __shfl_xor(s,  o, 64);
        ss += __shfl_xor(ss, o, 64);
    }
    float mu   = s * (1.0f / LATDIM);
    float var  = ss * (1.0f / LATDIM) - mu * mu;
    float rstd = rsqrtf(var + LN_EPS);
    float2 o2;
    o2.x = (v.x - mu) * rstd;
    o2.y = (v.y - mu) * rstd;
    ((float2*)(out + (size_t)row * LATDIM))[lane] = o2;
}

// 32 threads per edge; each thread handles 4 consecutive dims (float4 gather,
// 4 scalar fp32 atomics scatter). Coalesced 512B read per edge row.
__global__ __launch_bounds__(256) void spmm_kernel(const int* __restrict__ rowi,
                                                   const int* __restrict__ coli,
                                                   const float* __restrict__ vali,
                                                   const float* __restrict__ x,
                                                   float* __restrict__ y) {
    int t = blockIdx.x * 256 + threadIdx.x;
    int e = t >> 5;
    if (e >= N_EDGES) return;
    int k = t & 31;
    int r = rowi[e];
    int c = coli[e];
    float v = vali[e];
    float4 xv = ((const float4*)(x + (size_t)c * LATDIM))[k];
    float* yp = y + (size_t)r * LATDIM + k * 4;
    atomicAdd(yp + 0, v * xv.x);
    atomicAdd(yp + 1, v * xv.y);
    atomicAdd(yp + 2, v * xv.z);
    atomicAdd(yp + 3, v * xv.w);
}

// acc (+)= x ; optionally zero a retired buffer in the same pass.
__global__ __launch_bounds__(256) void addz_kernel(float* __restrict__ acc,
                                                   const float* __restrict__ x,
                                                   float* __restrict__ z,
                                                   int first) {
    size_t i = (size_t)blockIdx.x * 256 + threadIdx.x;  // float4 index
    float4 xv = ((const float4*)x)[i];
    float4* ap = ((float4*)acc) + i;
    if (first) {
        *ap = xv;
    } else {
        float4 a = *ap;
        a.x += xv.x; a.y += xv.y; a.z += xv.z; a.w += xv.w;
        *ap = a;
    }
    if (z) ((float4*)z)[i] = make_float4(0.f, 0.f, 0.f, 0.f);
}

extern "C" void kernel_launch(void* const* d_in, const int* in_sizes, int n_in,
                              void* d_out, int out_size, void* d_ws, size_t ws_size,
                              hipStream_t stream) {
    const float* embeds  = (const float*)d_in[0];
    const int*   adj_row = (const int*)d_in[1];
    const int*   adj_col = (const int*)d_in[2];
    const float* adj_val = (const float*)d_in[3];
    float* out = (float*)d_out;

    // Ping-pong x buffers in workspace (2 x 51.2 MB).
    float* A = (float*)d_ws;
    float* B = A + (size_t)N_NODES * LATDIM;

    const size_t rowBytes = (size_t)N_NODES * LATDIM * sizeof(float);
    const int lnGrid   = (N_NODES + 3) / 4;               // 25000
    const int spmmGrid = (N_EDGES * 32 + 255) / 256;      // 80000
    const int addGrid  = (N_NODES * LATDIM / 4 + 255) / 256;  // 12500

    // x0 = LayerNorm(embeds) -> A
    ln_kernel<<<lnGrid, 256, 0, stream>>>(embeds, A);
    // zero first spmm target (ws is poisoned 0xAA before every call)
    hipMemsetAsync(B, 0, rowBytes, stream);

    // layer 1: B = S @ A ; out = B ; A = 0
    spmm_kernel<<<spmmGrid, 256, 0, stream>>>(adj_row, adj_col, adj_val, A, B);
    addz_kernel<<<addGrid, 256, 0, stream>>>(out, B, A, 1);

    // layer 2: A = S @ B ; out += A ; B = 0
    spmm_kernel<<<spmmGrid, 256, 0, stream>>>(adj_row, adj_col, adj_val, B, A);
    addz_kernel<<<addGrid, 256, 0, stream>>>(out, A, B, 0);

    // layer 3: B = S @ A ; out += B
    spmm_kernel<<<spmmGrid, 256, 0, stream>>>(adj_row, adj_col, adj_val, A, B);
    addz_kernel<<<addGrid, 256, 0, stream>>>(out, B, nullptr, 0);
}

// Round 2
// 583.359 us; speedup vs baseline: 5.8223x; 5.8223x over previous
//
#include <hip/hip_runtime.h>

#define N_NODES 100000
#define N_EDGES 640000
#define LATDIM  128
#define LN_EPS  1e-5f

// ---------------- LayerNorm: one wave per row, float2 per lane ----------------
__global__ __launch_bounds__(256) void ln_kernel(const float* __restrict__ in,
                                                 float* __restrict__ out) {
    int row = blockIdx.x * 4 + (threadIdx.x >> 6);
    if (row >= N_NODES) return;
    int lane = threadIdx.x & 63;
    const float2* ip = (const float2*)(in + (size_t)row * LATDIM);
    float2 v = ip[lane];
    float s  = v.x + v.y;
    float ss = v.x * v.x + v.y * v.y;
    #pragma unroll
    for (int o = 32; o > 0; o >>= 1) {
        s  += __shfl_xor(s,  o, 64);
        ss += __shfl_xor(ss, o, 64);
    }
    float mu   = s * (1.0f / LATDIM);
    float var  = ss * (1.0f / LATDIM) - mu * mu;
    float rstd = rsqrtf(var + LN_EPS);
    float2 o2;
    o2.x = (v.x - mu) * rstd;
    o2.y = (v.y - mu) * rstd;
    ((float2*)(out + (size_t)row * LATDIM))[lane] = o2;
}

// ---------------- CSR build ----------------
__global__ __launch_bounds__(256) void hist_kernel(const int* __restrict__ rowi,
                                                   int* __restrict__ cnt) {
    int e = blockIdx.x * 256 + threadIdx.x;
    if (e < N_EDGES) atomicAdd(&cnt[rowi[e]], 1);
}

// Single-block exclusive scan over cnt[N_NODES], in place.
#define SCAN_T 1024
#define STRIP ((N_NODES + SCAN_T - 1) / SCAN_T)  // 98
__global__ __launch_bounds__(SCAN_T) void scan_kernel(int* __restrict__ cnt) {
    __shared__ int sums[SCAN_T];
    int t = threadIdx.x;
    int lo = t * STRIP;
    int hi = lo + STRIP; if (hi > N_NODES) hi = N_NODES;
    int s = 0;
    for (int i = lo; i < hi; ++i) s += cnt[i];
    sums[t] = s;
    __syncthreads();
    #pragma unroll
    for (int o = 1; o < SCAN_T; o <<= 1) {
        int v = 0;
        if (t >= o) v = sums[t - o];
        __syncthreads();
        if (t >= o) sums[t] += v;
        __syncthreads();
    }
    int off = (t > 0) ? sums[t - 1] : 0;
    for (int i = lo; i < hi; ++i) { int c = cnt[i]; cnt[i] = off; off += c; }
}

// Scatter edges into CSR order. cursor starts as exclusive prefix; after this
// kernel cursor[r] == inclusive end of row r (so cursor doubles as row_end).
__global__ __launch_bounds__(256) void scatter_kernel(const int* __restrict__ rowi,
                                                      const int* __restrict__ coli,
                                                      const float* __restrict__ vali,
                                                      int* __restrict__ cursor,
                                                      int* __restrict__ col_s,
                                                      float* __restrict__ val_s) {
    int e = blockIdx.x * 256 + threadIdx.x;
    if (e >= N_EDGES) return;
    int r = rowi[e];
    int pos = atomicAdd(&cursor[r], 1);
    col_s[pos] = coli[e];
    val_s[pos] = vali[e];
}

// ---------------- CSR SpMM: one wave per row, no atomics ----------------
// row_end[r] = inclusive prefix (post-scatter cursor). start = row? row_end[row-1] : 0.
__global__ __launch_bounds__(256) void spmm_csr_kernel(const int* __restrict__ row_end,
                                                       const int* __restrict__ col_s,
                                                       const float* __restrict__ val_s,
                                                       const float* __restrict__ x,
                                                       float* __restrict__ y,
                                                       float* __restrict__ acc,
                                                       int first, int store_x) {
    int row = blockIdx.x * 4 + (threadIdx.x >> 6);
    if (row >= N_NODES) return;
    int lane = threadIdx.x & 63;
    int end   = row_end[row];
    int start = row ? row_end[row - 1] : 0;
    const float2* x2 = (const float2*)x;
    float ax = 0.f, ay = 0.f;
    for (int e = start; e < end; ++e) {
        int   c = col_s[e];           // wave-uniform broadcast load
        float v = val_s[e];
        float2 xv = x2[(size_t)c * 64 + lane];
        ax += v * xv.x;
        ay += v * xv.y;
    }
    size_t oi = (size_t)row * 64 + lane;
    if (store_x) ((float2*)y)[oi] = make_float2(ax, ay);
    float2* a2 = (float2*)acc;
    if (first) {
        a2[oi] = make_float2(ax, ay);
    } else {
        float2 a = a2[oi];
        a2[oi] = make_float2(a.x + ax, a.y + ay);
    }
}

// ---------------- Fallback (atomic) path kernels, used only if ws too small ----
__global__ __launch_bounds__(256) void spmm_atomic_kernel(const int* __restrict__ rowi,
                                                          const int* __restrict__ coli,
                                                          const float* __restrict__ vali,
                                                          const float* __restrict__ x,
                                                          float* __restrict__ y) {
    int t = blockIdx.x * 256 + threadIdx.x;
    int e = t >> 5;
    if (e >= N_EDGES) return;
    int k = t & 31;
    int r = rowi[e];
    int c = coli[e];
    float v = vali[e];
    float4 xv = ((const float4*)(x + (size_t)c * LATDIM))[k];
    float* yp = y + (size_t)r * LATDIM + k * 4;
    atomicAdd(yp + 0, v * xv.x);
    atomicAdd(yp + 1, v * xv.y);
    atomicAdd(yp + 2, v * xv.z);
    atomicAdd(yp + 3, v * xv.w);
}

__global__ __launch_bounds__(256) void addz_kernel(float* __restrict__ acc,
                                                   const float* __restrict__ x,
                                                   float* __restrict__ z,
                                                   int first) {
    size_t i = (size_t)blockIdx.x * 256 + threadIdx.x;  // float4 index
    float4 xv = ((const float4*)x)[i];
    float4* ap = ((float4*)acc) + i;
    if (first) {
        *ap = xv;
    } else {
        float4 a = *ap;
        a.x += xv.x; a.y += xv.y; a.z += xv.z; a.w += xv.w;
        *ap = a;
    }
    if (z) ((float4*)z)[i] = make_float4(0.f, 0.f, 0.f, 0.f);
}

extern "C" void kernel_launch(void* const* d_in, const int* in_sizes, int n_in,
                              void* d_out, int out_size, void* d_ws, size_t ws_size,
                              hipStream_t stream) {
    const float* embeds  = (const float*)d_in[0];
    const int*   adj_row = (const int*)d_in[1];
    const int*   adj_col = (const int*)d_in[2];
    const float* adj_val = (const float*)d_in[3];
    float* out = (float*)d_out;

    float* A = (float*)d_ws;
    float* B = A + (size_t)N_NODES * LATDIM;
    int*   cnt   = (int*)(B + (size_t)N_NODES * LATDIM);   // N_NODES, becomes row_end
    int*   col_s = cnt + N_NODES;                           // N_EDGES
    float* val_s = (float*)(col_s + N_EDGES);               // N_EDGES
    size_t need  = (size_t)((char*)(val_s + N_EDGES) - (char*)d_ws);

    const int lnGrid   = N_NODES / 4;                 // 25000
    const int edgeGrid = (N_EDGES + 255) / 256;       // 2500
    const int rowGrid  = N_NODES / 4;                 // 25000 (wave per row)

    if (ws_size >= need) {
        // ---- CSR path ----
        ln_kernel<<<lnGrid, 256, 0, stream>>>(embeds, A);
        hipMemsetAsync(cnt, 0, (size_t)N_NODES * sizeof(int), stream);
        hist_kernel<<<edgeGrid, 256, 0, stream>>>(adj_row, cnt);
        scan_kernel<<<1, SCAN_T, 0, stream>>>(cnt);
        scatter_kernel<<<edgeGrid, 256, 0, stream>>>(adj_row, adj_col, adj_val,
                                                     cnt, col_s, val_s);
        // layer 1: B = S@A, out = B
        spmm_csr_kernel<<<rowGrid, 256, 0, stream>>>(cnt, col_s, val_s, A, B, out, 1, 1);
        // layer 2: A = S@B, out += A
        spmm_csr_kernel<<<rowGrid, 256, 0, stream>>>(cnt, col_s, val_s, B, A, out, 0, 1);
        // layer 3: out += S@A (x3 never stored)
        spmm_csr_kernel<<<rowGrid, 256, 0, stream>>>(cnt, col_s, val_s, A, B, out, 0, 0);
    } else {
        // ---- fallback: atomic path (round-1) ----
        const size_t rowBytes = (size_t)N_NODES * LATDIM * sizeof(float);
        const int spmmGrid = (N_EDGES * 32 + 255) / 256;
        const int addGrid  = (N_NODES * LATDIM / 4 + 255) / 256;
        ln_kernel<<<lnGrid, 256, 0, stream>>>(embeds, A);
        hipMemsetAsync(B, 0, rowBytes, stream);
        spmm_atomic_kernel<<<spmmGrid, 256, 0, stream>>>(adj_row, adj_col, adj_val, A, B);
        addz_kernel<<<addGrid, 256, 0, stream>>>(out, B, A, 1);
        spmm_atomic_kernel<<<spmmGrid, 256, 0, stream>>>(adj_row, adj_col, adj_val, B, A);
        addz_kernel<<<addGrid, 256, 0, stream>>>(out, A, B, 0);
        spmm_atomic_kernel<<<spmmGrid, 256, 0, stream>>>(adj_row, adj_col, adj_val, A, B);
        addz_kernel<<<addGrid, 256, 0, stream>>>(out, B, nullptr, 0);
    }
}

// Round 3
// 382.336 us; speedup vs baseline: 8.8835x; 1.5258x over previous
//
#include <hip/hip_runtime.h>

#define N_NODES 100000
#define N_EDGES 640000
#define LATDIM  128
#define LN_EPS  1e-5f

// scan geometry: 98 blocks x 1024 elements (256 threads x int4)
#define SCAN_NB   98
#define N_PAD     (SCAN_NB * 1024)   // 100352

// ---------------- LayerNorm: one wave per row, float2 per lane ----------------
__global__ __launch_bounds__(256) void ln_kernel(const float* __restrict__ in,
                                                 float* __restrict__ out) {
    int row = blockIdx.x * 4 + (threadIdx.x >> 6);
    if (row >= N_NODES) return;
    int lane = threadIdx.x & 63;
    const float2* ip = (const float2*)(in + (size_t)row * LATDIM);
    float2 v = ip[lane];
    float s  = v.x + v.y;
    float ss = v.x * v.x + v.y * v.y;
    #pragma unroll
    for (int o = 32; o > 0; o >>= 1) {
        s  += __shfl_xor(s,  o, 64);
        ss += __shfl_xor(ss, o, 64);
    }
    float mu   = s * (1.0f / LATDIM);
    float var  = ss * (1.0f / LATDIM) - mu * mu;
    float rstd = rsqrtf(var + LN_EPS);
    float2 o2;
    o2.x = (v.x - mu) * rstd;
    o2.y = (v.y - mu) * rstd;
    ((float2*)(out + (size_t)row * LATDIM))[lane] = o2;
}

// ---------------- CSR build ----------------
__global__ __launch_bounds__(256) void hist_kernel(const int* __restrict__ rowi,
                                                   int* __restrict__ cnt) {
    int e = blockIdx.x * 256 + threadIdx.x;
    if (e < N_EDGES) atomicAdd(&cnt[rowi[e]], 1);
}

// Phase A: per-block exclusive scan of 1024 ints (int4/thread), emit block sum.
__global__ __launch_bounds__(256) void scan_a_kernel(int* __restrict__ cnt,
                                                     int* __restrict__ bsums) {
    __shared__ int ts[256];
    int t = threadIdx.x;
    int base = blockIdx.x * 1024 + t * 4;          // always in-bounds (N_PAD)
    int4 v = *(const int4*)(cnt + base);
    int s = v.x + v.y + v.z + v.w;
    ts[t] = s;
    __syncthreads();
    #pragma unroll
    for (int o = 1; o < 256; o <<= 1) {
        int u = 0;
        if (t >= o) u = ts[t - o];
        __syncthreads();
        if (t >= o) ts[t] += u;
        __syncthreads();
    }
    int excl = ts[t] - s;                          // exclusive within block
    int4 w;
    w.x = excl;
    w.y = excl + v.x;
    w.z = excl + v.x + v.y;
    w.w = excl + v.x + v.y + v.z;
    *(int4*)(cnt + base) = w;
    if (t == 255) bsums[blockIdx.x] = ts[255];
}

// Phase B: exclusive scan of the 98 block sums, in place. One block.
__global__ __launch_bounds__(128) void scan_b_kernel(int* __restrict__ bsums) {
    __shared__ int ss[128];
    int t = threadIdx.x;
    int own = (t < SCAN_NB) ? bsums[t] : 0;
    ss[t] = own;
    __syncthreads();
    #pragma unroll
    for (int o = 1; o < 128; o <<= 1) {
        int u = 0;
        if (t >= o) u = ss[t - o];
        __syncthreads();
        if (t >= o) ss[t] += u;
        __syncthreads();
    }
    if (t < SCAN_NB) bsums[t] = ss[t] - own;       // exclusive
}

// Phase C: add block offsets.
__global__ __launch_bounds__(256) void scan_c_kernel(int* __restrict__ cnt,
                                                     const int* __restrict__ bsums) {
    int off = bsums[blockIdx.x];
    int base = blockIdx.x * 1024 + threadIdx.x * 4;
    int4 v = *(const int4*)(cnt + base);
    v.x += off; v.y += off; v.z += off; v.w += off;
    *(int4*)(cnt + base) = v;
}

// Scatter edges into CSR order. cursor starts as exclusive prefix; after this
// kernel cursor[r] == inclusive end of row r (so cursor doubles as row_end).
__global__ __launch_bounds__(256) void scatter_kernel(const int* __restrict__ rowi,
                                                      const int* __restrict__ coli,
                                                      const float* __restrict__ vali,
                                                      int* __restrict__ cursor,
                                                      int* __restrict__ col_s,
                                                      float* __restrict__ val_s) {
    int e = blockIdx.x * 256 + threadIdx.x;
    if (e >= N_EDGES) return;
    int r = rowi[e];
    int pos = atomicAdd(&cursor[r], 1);
    col_s[pos] = coli[e];
    val_s[pos] = vali[e];
}

// ---------------- CSR SpMM: one wave per row, no atomics ----------------
__global__ __launch_bounds__(256) void spmm_csr_kernel(const int* __restrict__ row_end,
                                                       const int* __restrict__ col_s,
                                                       const float* __restrict__ val_s,
                                                       const float* __restrict__ x,
                                                       float* __restrict__ y,
                                                       float* __restrict__ acc,
                                                       int first, int store_x) {
    int row = blockIdx.x * 4 + (threadIdx.x >> 6);
    if (row >= N_NODES) return;
    int lane = threadIdx.x & 63;
    int end   = row_end[row];
    int start = row ? row_end[row - 1] : 0;
    const float2* x2 = (const float2*)x;
    float ax = 0.f, ay = 0.f;
    int e = start;
    for (; e + 2 <= end; e += 2) {                 // unroll-2: two gathers in flight
        int   c0 = col_s[e],     c1 = col_s[e + 1];
        float v0 = val_s[e],     v1 = val_s[e + 1];
        float2 x0 = x2[(size_t)c0 * 64 + lane];
        float2 x1 = x2[(size_t)c1 * 64 + lane];
        ax += v0 * x0.x; ay += v0 * x0.y;
        ax += v1 * x1.x; ay += v1 * x1.y;
    }
    if (e < end) {
        int   c = col_s[e];
        float v = val_s[e];
        float2 xv = x2[(size_t)c * 64 + lane];
        ax += v * xv.x; ay += v * xv.y;
    }
    size_t oi = (size_t)row * 64 + lane;
    if (store_x) ((float2*)y)[oi] = make_float2(ax, ay);
    float2* a2 = (float2*)acc;
    if (first) {
        a2[oi] = make_float2(ax, ay);
    } else {
        float2 a = a2[oi];
        a2[oi] = make_float2(a.x + ax, a.y + ay);
    }
}

// ---------------- Fallback (atomic) path, used only if ws too small ----------
__global__ __launch_bounds__(256) void spmm_atomic_kernel(const int* __restrict__ rowi,
                                                          const int* __restrict__ coli,
                                                          const float* __restrict__ vali,
                                                          const float* __restrict__ x,
                                                          float* __restrict__ y) {
    int t = blockIdx.x * 256 + threadIdx.x;
    int e = t >> 5;
    if (e >= N_EDGES) return;
    int k = t & 31;
    int r = rowi[e];
    int c = coli[e];
    float v = vali[e];
    float4 xv = ((const float4*)(x + (size_t)c * LATDIM))[k];
    float* yp = y + (size_t)r * LATDIM + k * 4;
    atomicAdd(yp + 0, v * xv.x);
    atomicAdd(yp + 1, v * xv.y);
    atomicAdd(yp + 2, v * xv.z);
    atomicAdd(yp + 3, v * xv.w);
}

__global__ __launch_bounds__(256) void addz_kernel(float* __restrict__ acc,
                                                   const float* __restrict__ x,
                                                   float* __restrict__ z,
                                                   int first) {
    size_t i = (size_t)blockIdx.x * 256 + threadIdx.x;
    float4 xv = ((const float4*)x)[i];
    float4* ap = ((float4*)acc) + i;
    if (first) {
        *ap = xv;
    } else {
        float4 a = *ap;
        a.x += xv.x; a.y += xv.y; a.z += xv.z; a.w += xv.w;
        *ap = a;
    }
    if (z) ((float4*)z)[i] = make_float4(0.f, 0.f, 0.f, 0.f);
}

extern "C" void kernel_launch(void* const* d_in, const int* in_sizes, int n_in,
                              void* d_out, int out_size, void* d_ws, size_t ws_size,
                              hipStream_t stream) {
    const float* embeds  = (const float*)d_in[0];
    const int*   adj_row = (const int*)d_in[1];
    const int*   adj_col = (const int*)d_in[2];
    const float* adj_val = (const float*)d_in[3];
    float* out = (float*)d_out;

    float* A = (float*)d_ws;
    float* B = A + (size_t)N_NODES * LATDIM;
    int*   cnt   = (int*)(B + (size_t)N_NODES * LATDIM);   // N_PAD ints -> row_end
    int*   bsums = cnt + N_PAD;                            // SCAN_NB (+pad to 128)
    int*   col_s = bsums + 128;                            // N_EDGES
    float* val_s = (float*)(col_s + N_EDGES);              // N_EDGES
    size_t need  = (size_t)((char*)(val_s + N_EDGES) - (char*)d_ws);

    const int lnGrid   = N_NODES / 4;                 // 25000
    const int edgeGrid = (N_EDGES + 255) / 256;       // 2500
    const int rowGrid  = N_NODES / 4;                 // 25000 (wave per row)

    if (ws_size >= need) {
        // ---- CSR path ----
        ln_kernel<<<lnGrid, 256, 0, stream>>>(embeds, A);
        hipMemsetAsync(cnt, 0, (size_t)N_PAD * sizeof(int), stream);
        hist_kernel<<<edgeGrid, 256, 0, stream>>>(adj_row, cnt);
        scan_a_kernel<<<SCAN_NB, 256, 0, stream>>>(cnt, bsums);
        scan_b_kernel<<<1, 128, 0, stream>>>(bsums);
        scan_c_kernel<<<SCAN_NB, 256, 0, stream>>>(cnt, bsums);
        scatter_kernel<<<edgeGrid, 256, 0, stream>>>(adj_row, adj_col, adj_val,
                                                     cnt, col_s, val_s);
        // layer 1: B = S@A, out = B
        spmm_csr_kernel<<<rowGrid, 256, 0, stream>>>(cnt, col_s, val_s, A, B, out, 1, 1);
        // layer 2: A = S@B, out += A
        spmm_csr_kernel<<<rowGrid, 256, 0, stream>>>(cnt, col_s, val_s, B, A, out, 0, 1);
        // layer 3: out += S@A (x3 never stored)
        spmm_csr_kernel<<<rowGrid, 256, 0, stream>>>(cnt, col_s, val_s, A, B, out, 0, 0);
    } else {
        // ---- fallback: atomic path ----
        const size_t rowBytes = (size_t)N_NODES * LATDIM * sizeof(float);
        const int spmmGrid = (N_EDGES * 32 + 255) / 256;
        const int addGrid  = (N_NODES * LATDIM / 4 + 255) / 256;
        ln_kernel<<<lnGrid, 256, 0, stream>>>(embeds, A);
        hipMemsetAsync(B, 0, rowBytes, stream);
        spmm_atomic_kernel<<<spmmGrid, 256, 0, stream>>>(adj_row, adj_col, adj_val, A, B);
        addz_kernel<<<addGrid, 256, 0, stream>>>(out, B, A, 1);
        spmm_atomic_kernel<<<spmmGrid, 256, 0, stream>>>(adj_row, adj_col, adj_val, B, A);
        addz_kernel<<<addGrid, 256, 0, stream>>>(out, A, B, 0);
        spmm_atomic_kernel<<<spmmGrid, 256, 0, stream>>>(adj_row, adj_col, adj_val, A, B);
        addz_kernel<<<addGrid, 256, 0, stream>>>(out, B, nullptr, 0);
    }
}

// Round 4
// 340.156 us; speedup vs baseline: 9.9851x; 1.1240x over previous
//
#include <hip/hip_runtime.h>

#define N_NODES 100000
#define N_EDGES 640000
#define LATDIM  128
#define LN_EPS  1e-5f

// scan geometry: 98 blocks x 1024 elements (256 threads x int4)
#define SCAN_NB   98
#define N_PAD     (SCAN_NB * 1024)   // 100352

// ---------------- LayerNorm: half-wave (32 lanes) per row, float4 per lane ----
__global__ __launch_bounds__(256) void ln_kernel(const float* __restrict__ in,
                                                 float* __restrict__ out) {
    int tid  = threadIdx.x;
    int wave = tid >> 6;
    int lane = tid & 63;
    int half = lane >> 5;
    int sub  = lane & 31;
    int row  = blockIdx.x * 8 + wave * 2 + half;   // grid sized exactly
    const float4* ip = (const float4*)in;
    float4 v = ip[(size_t)row * 32 + sub];
    float s  = v.x + v.y + v.z + v.w;
    float ss = v.x * v.x + v.y * v.y + v.z * v.z + v.w * v.w;
    #pragma unroll
    for (int o = 16; o > 0; o >>= 1) {             // reduce within 32-lane half
        s  += __shfl_xor(s,  o, 64);
        ss += __shfl_xor(ss, o, 64);
    }
    float mu   = s * (1.0f / LATDIM);
    float var  = ss * (1.0f / LATDIM) - mu * mu;
    float rstd = rsqrtf(var + LN_EPS);
    float4 o4;
    o4.x = (v.x - mu) * rstd;
    o4.y = (v.y - mu) * rstd;
    o4.z = (v.z - mu) * rstd;
    o4.w = (v.w - mu) * rstd;
    ((float4*)out)[(size_t)row * 32 + sub] = o4;
}

// ---------------- CSR build ----------------
__global__ __launch_bounds__(256) void hist_kernel(const int* __restrict__ rowi,
                                                   int* __restrict__ cnt) {
    int e = blockIdx.x * 256 + threadIdx.x;
    if (e < N_EDGES) atomicAdd(&cnt[rowi[e]], 1);
}

// Phase A: per-block exclusive scan of 1024 ints (int4/thread), emit block sum.
__global__ __launch_bounds__(256) void scan_a_kernel(int* __restrict__ cnt,
                                                     int* __restrict__ bsums) {
    __shared__ int ts[256];
    int t = threadIdx.x;
    int base = blockIdx.x * 1024 + t * 4;
    int4 v = *(const int4*)(cnt + base);
    int s = v.x + v.y + v.z + v.w;
    ts[t] = s;
    __syncthreads();
    #pragma unroll
    for (int o = 1; o < 256; o <<= 1) {
        int u = 0;
        if (t >= o) u = ts[t - o];
        __syncthreads();
        if (t >= o) ts[t] += u;
        __syncthreads();
    }
    int excl = ts[t] - s;
    int4 w;
    w.x = excl;
    w.y = excl + v.x;
    w.z = excl + v.x + v.y;
    w.w = excl + v.x + v.y + v.z;
    *(int4*)(cnt + base) = w;
    if (t == 255) bsums[blockIdx.x] = ts[255];
}

// Phase B: exclusive scan of the 98 block sums, in place. One block.
__global__ __launch_bounds__(128) void scan_b_kernel(int* __restrict__ bsums) {
    __shared__ int ss[128];
    int t = threadIdx.x;
    int own = (t < SCAN_NB) ? bsums[t] : 0;
    ss[t] = own;
    __syncthreads();
    #pragma unroll
    for (int o = 1; o < 128; o <<= 1) {
        int u = 0;
        if (t >= o) u = ss[t - o];
        __syncthreads();
        if (t >= o) ss[t] += u;
        __syncthreads();
    }
    if (t < SCAN_NB) bsums[t] = ss[t] - own;
}

// Phase C: add block offsets.
__global__ __launch_bounds__(256) void scan_c_kernel(int* __restrict__ cnt,
                                                     const int* __restrict__ bsums) {
    int off = bsums[blockIdx.x];
    int base = blockIdx.x * 1024 + threadIdx.x * 4;
    int4 v = *(const int4*)(cnt + base);
    v.x += off; v.y += off; v.z += off; v.w += off;
    *(int4*)(cnt + base) = v;
}

// Scatter edges into CSR order as interleaved (col, val) 8B pairs.
// cursor starts as exclusive prefix; afterwards cursor[r] == row_end[r].
__global__ __launch_bounds__(256) void scatter_kernel(const int* __restrict__ rowi,
                                                      const int* __restrict__ coli,
                                                      const float* __restrict__ vali,
                                                      int* __restrict__ cursor,
                                                      int2* __restrict__ pairs) {
    int e = blockIdx.x * 256 + threadIdx.x;
    if (e >= N_EDGES) return;
    int r = rowi[e];
    int pos = atomicAdd(&cursor[r], 1);
    pairs[pos] = make_int2(coli[e], __float_as_int(vali[e]));
}

// ---------------- CSR SpMM: 2 rows per wave (32 lanes x float4), no atomics ----
// mode 0: y[row] = S@x        (store x_k for next layer)
// mode 2: out[row] = S@x + add0[row] + add1[row]   (final layer, no y store)
__global__ __launch_bounds__(256) void spmm_csr_kernel(const int* __restrict__ row_end,
                                                       const int2* __restrict__ pairs,
                                                       const float* __restrict__ x,
                                                       float* __restrict__ y,
                                                       const float* __restrict__ add0,
                                                       const float* __restrict__ add1,
                                                       float* __restrict__ out,
                                                       int mode) {
    int tid  = threadIdx.x;
    int wave = tid >> 6;
    int lane = tid & 63;
    int half = lane >> 5;
    int sub  = lane & 31;
    int row  = blockIdx.x * 8 + wave * 2 + half;   // grid sized exactly
    int end   = row_end[row];
    int start = row ? row_end[row - 1] : 0;
    const float4* x4 = (const float4*)x;
    float4 a = make_float4(0.f, 0.f, 0.f, 0.f);
    int e = start;
    for (; e + 2 <= end; e += 2) {                 // two gathers in flight
        int2 p0 = pairs[e];
        int2 p1 = pairs[e + 1];
        float4 g0 = x4[(size_t)p0.x * 32 + sub];
        float4 g1 = x4[(size_t)p1.x * 32 + sub];
        float v0 = __int_as_float(p0.y);
        float v1 = __int_as_float(p1.y);
        a.x += v0 * g0.x; a.y += v0 * g0.y; a.z += v0 * g0.z; a.w += v0 * g0.w;
        a.x += v1 * g1.x; a.y += v1 * g1.y; a.z += v1 * g1.z; a.w += v1 * g1.w;
    }
    if (e < end) {
        int2 p = pairs[e];
        float4 g = x4[(size_t)p.x * 32 + sub];
        float v = __int_as_float(p.y);
        a.x += v * g.x; a.y += v * g.y; a.z += v * g.z; a.w += v * g.w;
    }
    size_t oi = (size_t)row * 32 + sub;
    if (mode == 2) {
        float4 b0 = ((const float4*)add0)[oi];
        float4 b1 = ((const float4*)add1)[oi];
        ((float4*)out)[oi] = make_float4(a.x + b0.x + b1.x,
                                         a.y + b0.y + b1.y,
                                         a.z + b0.z + b1.z,
                                         a.w + b0.w + b1.w);
    } else {
        ((float4*)y)[oi] = a;
    }
}

// ---------------- Fallback (atomic) path, used only if ws too small ----------
__global__ __launch_bounds__(256) void spmm_atomic_kernel(const int* __restrict__ rowi,
                                                          const int* __restrict__ coli,
                                                          const float* __restrict__ vali,
                                                          const float* __restrict__ x,
                                                          float* __restrict__ y) {
    int t = blockIdx.x * 256 + threadIdx.x;
    int e = t >> 5;
    if (e >= N_EDGES) return;
    int k = t & 31;
    int r = rowi[e];
    int c = coli[e];
    float v = vali[e];
    float4 xv = ((const float4*)(x + (size_t)c * LATDIM))[k];
    float* yp = y + (size_t)r * LATDIM + k * 4;
    atomicAdd(yp + 0, v * xv.x);
    atomicAdd(yp + 1, v * xv.y);
    atomicAdd(yp + 2, v * xv.z);
    atomicAdd(yp + 3, v * xv.w);
}

__global__ __launch_bounds__(256) void addz_kernel(float* __restrict__ acc,
                                                   const float* __restrict__ x,
                                                   float* __restrict__ z,
                                                   int first) {
    size_t i = (size_t)blockIdx.x * 256 + threadIdx.x;
    float4 xv = ((const float4*)x)[i];
    float4* ap = ((float4*)acc) + i;
    if (first) {
        *ap = xv;
    } else {
        float4 a = *ap;
        a.x += xv.x; a.y += xv.y; a.z += xv.z; a.w += xv.w;
        *ap = a;
    }
    if (z) ((float4*)z)[i] = make_float4(0.f, 0.f, 0.f, 0.f);
}

extern "C" void kernel_launch(void* const* d_in, const int* in_sizes, int n_in,
                              void* d_out, int out_size, void* d_ws, size_t ws_size,
                              hipStream_t stream) {
    const float* embeds  = (const float*)d_in[0];
    const int*   adj_row = (const int*)d_in[1];
    const int*   adj_col = (const int*)d_in[2];
    const float* adj_val = (const float*)d_in[3];
    float* out = (float*)d_out;

    float* A = (float*)d_ws;
    float* B = A + (size_t)N_NODES * LATDIM;
    int*   cnt   = (int*)(B + (size_t)N_NODES * LATDIM);   // N_PAD ints -> row_end
    int*   bsums = cnt + N_PAD;                            // SCAN_NB (padded to 128)
    int2*  pairs = (int2*)(bsums + 128);                   // N_EDGES 8B pairs
    size_t need  = (size_t)((char*)(pairs + N_EDGES) - (char*)d_ws);

    const int lnGrid   = N_NODES / 8;                 // 12500 (8 rows/block)
    const int edgeGrid = (N_EDGES + 255) / 256;       // 2500
    const int rowGrid  = N_NODES / 8;                 // 12500 (2 rows/wave)

    if (ws_size >= need) {
        // ---- CSR path ----
        ln_kernel<<<lnGrid, 256, 0, stream>>>(embeds, A);
        hipMemsetAsync(cnt, 0, (size_t)N_PAD * sizeof(int), stream);
        hist_kernel<<<edgeGrid, 256, 0, stream>>>(adj_row, cnt);
        scan_a_kernel<<<SCAN_NB, 256, 0, stream>>>(cnt, bsums);
        scan_b_kernel<<<1, 128, 0, stream>>>(bsums);
        scan_c_kernel<<<SCAN_NB, 256, 0, stream>>>(cnt, bsums);
        scatter_kernel<<<edgeGrid, 256, 0, stream>>>(adj_row, adj_col, adj_val,
                                                     cnt, pairs);
        // layer 1: B = S@A
        spmm_csr_kernel<<<rowGrid, 256, 0, stream>>>(cnt, pairs, A, B,
                                                     nullptr, nullptr, nullptr, 0);
        // layer 2: A' = S@B   (x2 overwrites x0 buffer)
        spmm_csr_kernel<<<rowGrid, 256, 0, stream>>>(cnt, pairs, B, A,
                                                     nullptr, nullptr, nullptr, 0);
        // layer 3: out = S@A' + B(x1) + A'(x2)
        spmm_csr_kernel<<<rowGrid, 256, 0, stream>>>(cnt, pairs, A, nullptr,
                                                     B, A, out, 2);
    } else {
        // ---- fallback: atomic path ----
        const size_t rowBytes = (size_t)N_NODES * LATDIM * sizeof(float);
        const int spmmGrid = (N_EDGES * 32 + 255) / 256;
        const int addGrid  = (N_NODES * LATDIM / 4 + 255) / 256;
        const int lnGrid4  = (N_NODES + 7) / 8;
        ln_kernel<<<lnGrid4, 256, 0, stream>>>(embeds, A);
        hipMemsetAsync(B, 0, rowBytes, stream);
        spmm_atomic_kernel<<<spmmGrid, 256, 0, stream>>>(adj_row, adj_col, adj_val, A, B);
        addz_kernel<<<addGrid, 256, 0, stream>>>(out, B, A, 1);
        spmm_atomic_kernel<<<spmmGrid, 256, 0, stream>>>(adj_row, adj_col, adj_val, B, A);
        addz_kernel<<<addGrid, 256, 0, stream>>>(out, A, B, 0);
        spmm_atomic_kernel<<<spmmGrid, 256, 0, stream>>>(adj_row, adj_col, adj_val, A, B);
        addz_kernel<<<addGrid, 256, 0, stream>>>(out, B, nullptr, 0);
    }
}

// Round 5
// 282.196 us; speedup vs baseline: 12.0359x; 1.2054x over previous
//
#include <hip/hip_runtime.h>

#define N_NODES 100000
#define N_EDGES 640000
#define LATDIM  128
#define LN_EPS  1e-5f

typedef unsigned int u32;

// scan geometry: 98 blocks x 1024 elements (256 threads x int4)
#define SCAN_NB   98
#define N_PAD     (SCAN_NB * 1024)   // 100352

// ---- bf16 helpers (packed 2x bf16 per u32, element 0 in low half) ----
__device__ __forceinline__ float bflo(u32 u) { return __uint_as_float(u << 16); }
__device__ __forceinline__ float bfhi(u32 u) { return __uint_as_float(u & 0xffff0000u); }
__device__ __forceinline__ u32 pack_bf2(float a, float b) {
    u32 ua = __float_as_uint(a), ub = __float_as_uint(b);
    ua = (ua + 0x7fffu + ((ua >> 16) & 1u)) >> 16;          // RNE
    ub = (ub + 0x7fffu + ((ub >> 16) & 1u)) >> 16;
    return ua | (ub << 16);
}

// ---------------- LayerNorm -> bf16: half-wave (32 lanes) per row --------------
__global__ __launch_bounds__(256) void ln_bf16_kernel(const float* __restrict__ in,
                                                      u32* __restrict__ out) {
    int tid  = threadIdx.x;
    int wave = tid >> 6;
    int lane = tid & 63;
    int half = lane >> 5;
    int sub  = lane & 31;
    int row  = blockIdx.x * 8 + wave * 2 + half;
    float4 v = ((const float4*)in)[(size_t)row * 32 + sub];
    float s  = v.x + v.y + v.z + v.w;
    float ss = v.x * v.x + v.y * v.y + v.z * v.z + v.w * v.w;
    #pragma unroll
    for (int o = 16; o > 0; o >>= 1) {
        s  += __shfl_xor(s,  o, 64);
        ss += __shfl_xor(ss, o, 64);
    }
    float mu   = s * (1.0f / LATDIM);
    float var  = ss * (1.0f / LATDIM) - mu * mu;
    float rstd = rsqrtf(var + LN_EPS);
    uint2 w;
    w.x = pack_bf2((v.x - mu) * rstd, (v.y - mu) * rstd);
    w.y = pack_bf2((v.z - mu) * rstd, (v.w - mu) * rstd);
    ((uint2*)out)[(size_t)row * 32 + sub] = w;
}

// ---------------- CSR build ----------------
__global__ __launch_bounds__(256) void hist_kernel(const int* __restrict__ rowi,
                                                   int* __restrict__ cnt) {
    int e = blockIdx.x * 256 + threadIdx.x;
    if (e < N_EDGES) atomicAdd(&cnt[rowi[e]], 1);
}

__global__ __launch_bounds__(256) void scan_a_kernel(int* __restrict__ cnt,
                                                     int* __restrict__ bsums) {
    __shared__ int ts[256];
    int t = threadIdx.x;
    int base = blockIdx.x * 1024 + t * 4;
    int4 v = *(const int4*)(cnt + base);
    int s = v.x + v.y + v.z + v.w;
    ts[t] = s;
    __syncthreads();
    #pragma unroll
    for (int o = 1; o < 256; o <<= 1) {
        int u = 0;
        if (t >= o) u = ts[t - o];
        __syncthreads();
        if (t >= o) ts[t] += u;
        __syncthreads();
    }
    int excl = ts[t] - s;
    int4 w;
    w.x = excl;
    w.y = excl + v.x;
    w.z = excl + v.x + v.y;
    w.w = excl + v.x + v.y + v.z;
    *(int4*)(cnt + base) = w;
    if (t == 255) bsums[blockIdx.x] = ts[255];
}

__global__ __launch_bounds__(128) void scan_b_kernel(int* __restrict__ bsums) {
    __shared__ int ss[128];
    int t = threadIdx.x;
    int own = (t < SCAN_NB) ? bsums[t] : 0;
    ss[t] = own;
    __syncthreads();
    #pragma unroll
    for (int o = 1; o < 128; o <<= 1) {
        int u = 0;
        if (t >= o) u = ss[t - o];
        __syncthreads();
        if (t >= o) ss[t] += u;
        __syncthreads();
    }
    if (t < SCAN_NB) bsums[t] = ss[t] - own;
}

__global__ __launch_bounds__(256) void scan_c_kernel(int* __restrict__ cnt,
                                                     const int* __restrict__ bsums) {
    int off = bsums[blockIdx.x];
    int base = blockIdx.x * 1024 + threadIdx.x * 4;
    int4 v = *(const int4*)(cnt + base);
    v.x += off; v.y += off; v.z += off; v.w += off;
    *(int4*)(cnt + base) = v;
}

__global__ __launch_bounds__(256) void scatter_kernel(const int* __restrict__ rowi,
                                                      const int* __restrict__ coli,
                                                      const float* __restrict__ vali,
                                                      int* __restrict__ cursor,
                                                      int2* __restrict__ pairs) {
    int e = blockIdx.x * 256 + threadIdx.x;
    if (e >= N_EDGES) return;
    int r = rowi[e];
    int pos = atomicAdd(&cursor[r], 1);
    pairs[pos] = make_int2(coli[e], __float_as_int(vali[e]));
}

// ---------------- CSR SpMM over bf16 x: 4 rows/wave (16 lanes x 8 dims) -------
// mode 0: y[row] = bf16(S@x)
// mode 2: out[row] = fp32( S@x + add0[row] + add1[row] )
__global__ __launch_bounds__(256) void spmm_csr_kernel(const int* __restrict__ row_end,
                                                       const int2* __restrict__ pairs,
                                                       const u32* __restrict__ x,
                                                       u32* __restrict__ y,
                                                       const u32* __restrict__ add0,
                                                       const u32* __restrict__ add1,
                                                       float* __restrict__ out,
                                                       int mode) {
    int tid  = threadIdx.x;
    int wave = tid >> 6;
    int lane = tid & 63;
    int row  = blockIdx.x * 16 + wave * 4 + (lane >> 4);
    int sub  = lane & 15;                          // owns dims [sub*8, sub*8+8)
    int end   = row_end[row];
    int e     = row ? row_end[row - 1] : 0;
    const uint4* x4 = (const uint4*)x;             // 16 uint4 per row
    float a0=0,a1=0,a2=0,a3=0,a4=0,a5=0,a6=0,a7=0;
    for (; e < end; ++e) {
        int2 p = pairs[e];
        uint4 g = x4[(size_t)p.x * 16 + sub];
        float v = __int_as_float(p.y);
        a0 += v * bflo(g.x); a1 += v * bfhi(g.x);
        a2 += v * bflo(g.y); a3 += v * bfhi(g.y);
        a4 += v * bflo(g.z); a5 += v * bfhi(g.z);
        a6 += v * bflo(g.w); a7 += v * bfhi(g.w);
    }
    size_t oi = (size_t)row * 16 + sub;
    if (mode == 2) {
        uint4 b0 = ((const uint4*)add0)[oi];
        uint4 b1 = ((const uint4*)add1)[oi];
        a0 += bflo(b0.x) + bflo(b1.x); a1 += bfhi(b0.x) + bfhi(b1.x);
        a2 += bflo(b0.y) + bflo(b1.y); a3 += bfhi(b0.y) + bfhi(b1.y);
        a4 += bflo(b0.z) + bflo(b1.z); a5 += bfhi(b0.z) + bfhi(b1.z);
        a6 += bflo(b0.w) + bflo(b1.w); a7 += bfhi(b0.w) + bfhi(b1.w);
        float4* o4 = (float4*)(out + (size_t)row * LATDIM + sub * 8);
        o4[0] = make_float4(a0, a1, a2, a3);
        o4[1] = make_float4(a4, a5, a6, a7);
    } else {
        uint4 w;
        w.x = pack_bf2(a0, a1);
        w.y = pack_bf2(a2, a3);
        w.z = pack_bf2(a4, a5);
        w.w = pack_bf2(a6, a7);
        ((uint4*)y)[oi] = w;
    }
}

// ---------------- Fallback (atomic, fp32) path -------------------------------
__global__ __launch_bounds__(256) void ln_f32_kernel(const float* __restrict__ in,
                                                     float* __restrict__ out) {
    int tid  = threadIdx.x;
    int wave = tid >> 6;
    int lane = tid & 63;
    int half = lane >> 5;
    int sub  = lane & 31;
    int row  = blockIdx.x * 8 + wave * 2 + half;
    if (row >= N_NODES) return;
    float4 v = ((const float4*)in)[(size_t)row * 32 + sub];
    float s  = v.x + v.y + v.z + v.w;
    float ss = v.x * v.x + v.y * v.y + v.z * v.z + v.w * v.w;
    #pragma unroll
    for (int o = 16; o > 0; o >>= 1) {
        s  += __shfl_xor(s,  o, 64);
        ss += __shfl_xor(ss, o, 64);
    }
    float mu   = s * (1.0f / LATDIM);
    float var  = ss * (1.0f / LATDIM) - mu * mu;
    float rstd = rsqrtf(var + LN_EPS);
    float4 o4;
    o4.x = (v.x - mu) * rstd; o4.y = (v.y - mu) * rstd;
    o4.z = (v.z - mu) * rstd; o4.w = (v.w - mu) * rstd;
    ((float4*)out)[(size_t)row * 32 + sub] = o4;
}

__global__ __launch_bounds__(256) void spmm_atomic_kernel(const int* __restrict__ rowi,
                                                          const int* __restrict__ coli,
                                                          const float* __restrict__ vali,
                                                          const float* __restrict__ x,
                                                          float* __restrict__ y) {
    int t = blockIdx.x * 256 + threadIdx.x;
    int e = t >> 5;
    if (e >= N_EDGES) return;
    int k = t & 31;
    int r = rowi[e];
    int c = coli[e];
    float v = vali[e];
    float4 xv = ((const float4*)(x + (size_t)c * LATDIM))[k];
    float* yp = y + (size_t)r * LATDIM + k * 4;
    atomicAdd(yp + 0, v * xv.x);
    atomicAdd(yp + 1, v * xv.y);
    atomicAdd(yp + 2, v * xv.z);
    atomicAdd(yp + 3, v * xv.w);
}

__global__ __launch_bounds__(256) void addz_kernel(float* __restrict__ acc,
                                                   const float* __restrict__ x,
                                                   float* __restrict__ z,
                                                   int first) {
    size_t i = (size_t)blockIdx.x * 256 + threadIdx.x;
    float4 xv = ((const float4*)x)[i];
    float4* ap = ((float4*)acc) + i;
    if (first) {
        *ap = xv;
    } else {
        float4 a = *ap;
        a.x += xv.x; a.y += xv.y; a.z += xv.z; a.w += xv.w;
        *ap = a;
    }
    if (z) ((float4*)z)[i] = make_float4(0.f, 0.f, 0.f, 0.f);
}

extern "C" void kernel_launch(void* const* d_in, const int* in_sizes, int n_in,
                              void* d_out, int out_size, void* d_ws, size_t ws_size,
                              hipStream_t stream) {
    const float* embeds  = (const float*)d_in[0];
    const int*   adj_row = (const int*)d_in[1];
    const int*   adj_col = (const int*)d_in[2];
    const float* adj_val = (const float*)d_in[3];
    float* out = (float*)d_out;

    // CSR-path layout: two bf16 x buffers + cnt + bsums + pairs
    u32*  A16  = (u32*)d_ws;                                   // 6.4M u32 = 25.6 MB
    u32*  B16  = A16 + (size_t)N_NODES * (LATDIM / 2);
    int*  cnt   = (int*)(B16 + (size_t)N_NODES * (LATDIM / 2)); // N_PAD ints
    int*  bsums = cnt + N_PAD;                                  // padded to 128
    int2* pairs = (int2*)(bsums + 128);                         // N_EDGES pairs
    size_t need = (size_t)((char*)(pairs + N_EDGES) - (char*)d_ws);

    const int lnGrid   = N_NODES / 8;                 // 12500
    const int edgeGrid = (N_EDGES + 255) / 256;       // 2500
    const int rowGrid  = N_NODES / 16;                // 6250 (4 rows/wave)

    if (ws_size >= need) {
        // ---- CSR bf16 path ----
        ln_bf16_kernel<<<lnGrid, 256, 0, stream>>>(embeds, A16);
        hipMemsetAsync(cnt, 0, (size_t)N_PAD * sizeof(int), stream);
        hist_kernel<<<edgeGrid, 256, 0, stream>>>(adj_row, cnt);
        scan_a_kernel<<<SCAN_NB, 256, 0, stream>>>(cnt, bsums);
        scan_b_kernel<<<1, 128, 0, stream>>>(bsums);
        scan_c_kernel<<<SCAN_NB, 256, 0, stream>>>(cnt, bsums);
        scatter_kernel<<<edgeGrid, 256, 0, stream>>>(adj_row, adj_col, adj_val,
                                                     cnt, pairs);
        // layer 1: B16 = S@A16 (x1)
        spmm_csr_kernel<<<rowGrid, 256, 0, stream>>>(cnt, pairs, A16, B16,
                                                     nullptr, nullptr, nullptr, 0);
        // layer 2: A16 = S@B16 (x2, overwrites x0)
        spmm_csr_kernel<<<rowGrid, 256, 0, stream>>>(cnt, pairs, B16, A16,
                                                     nullptr, nullptr, nullptr, 0);
        // layer 3: out = S@A16 + B16(x1) + A16(x2), fp32
        spmm_csr_kernel<<<rowGrid, 256, 0, stream>>>(cnt, pairs, A16, nullptr,
                                                     B16, A16, out, 2);
    } else {
        // ---- fallback: fp32 atomic path ----
        float* A = (float*)d_ws;
        float* B = A + (size_t)N_NODES * LATDIM;
        const size_t rowBytes = (size_t)N_NODES * LATDIM * sizeof(float);
        const int spmmGrid = (N_EDGES * 32 + 255) / 256;
        const int addGrid  = (N_NODES * LATDIM / 4 + 255) / 256;
        ln_f32_kernel<<<lnGrid, 256, 0, stream>>>(embeds, A);
        hipMemsetAsync(B, 0, rowBytes, stream);
        spmm_atomic_kernel<<<spmmGrid, 256, 0, stream>>>(adj_row, adj_col, adj_val, A, B);
        addz_kernel<<<addGrid, 256, 0, stream>>>(out, B, A, 1);
        spmm_atomic_kernel<<<spmmGrid, 256, 0, stream>>>(adj_row, adj_col, adj_val, B, A);
        addz_kernel<<<addGrid, 256, 0, stream>>>(out, A, B, 0);
        spmm_atomic_kernel<<<spmmGrid, 256, 0, stream>>>(adj_row, adj_col, adj_val, A, B);
        addz_kernel<<<addGrid, 256, 0, stream>>>(out, B, nullptr, 0);
    }
}

// Round 7
// 279.177 us; speedup vs baseline: 12.1661x; 1.0108x over previous
//
#include <hip/hip_runtime.h>

#define N_NODES 100000
#define N_EDGES 640000
#define LATDIM  128
#define LN_EPS  1e-5f

typedef unsigned int u32;
typedef float f32x4 __attribute__((ext_vector_type(4)));   // native vector for nt ld/st

// scan geometry: 98 blocks x 1024 elements (256 threads x int4)
#define SCAN_NB   98
#define N_PAD     (SCAN_NB * 1024)   // 100352

#define LN_BLOCKS   (N_NODES / 8)            // 12500
#define HIST_BLOCKS ((N_EDGES + 255) / 256)  // 2500

// ---- bf16 helpers (packed 2x bf16 per u32, element 0 in low half) ----
__device__ __forceinline__ float bflo(u32 u) { return __uint_as_float(u << 16); }
__device__ __forceinline__ float bfhi(u32 u) { return __uint_as_float(u & 0xffff0000u); }
__device__ __forceinline__ u32 pack_bf2(float a, float b) {
    u32 ua = __float_as_uint(a), ub = __float_as_uint(b);
    ua = (ua + 0x7fffu + ((ua >> 16) & 1u)) >> 16;          // RNE
    ub = (ub + 0x7fffu + ((ub >> 16) & 1u)) >> 16;
    return ua | (ub << 16);
}

// ------------- fused LayerNorm(->bf16) + row histogram (disjoint blocks) ------
__global__ __launch_bounds__(256) void ln_hist_kernel(const float* __restrict__ in,
                                                      u32* __restrict__ out,
                                                      const int* __restrict__ rowi,
                                                      int* __restrict__ cnt) {
    int b = blockIdx.x;
    if (b < LN_BLOCKS) {
        int tid  = threadIdx.x;
        int wave = tid >> 6;
        int lane = tid & 63;
        int half = lane >> 5;
        int sub  = lane & 31;
        int row  = b * 8 + wave * 2 + half;
        f32x4 v = __builtin_nontemporal_load(((const f32x4*)in) + (size_t)row * 32 + sub);
        float s  = v.x + v.y + v.z + v.w;
        float ss = v.x * v.x + v.y * v.y + v.z * v.z + v.w * v.w;
        #pragma unroll
        for (int o = 16; o > 0; o >>= 1) {
            s  += __shfl_xor(s,  o, 64);
            ss += __shfl_xor(ss, o, 64);
        }
        float mu   = s * (1.0f / LATDIM);
        float var  = ss * (1.0f / LATDIM) - mu * mu;
        float rstd = rsqrtf(var + LN_EPS);
        uint2 w;
        w.x = pack_bf2((v.x - mu) * rstd, (v.y - mu) * rstd);
        w.y = pack_bf2((v.z - mu) * rstd, (v.w - mu) * rstd);
        ((uint2*)out)[(size_t)row * 32 + sub] = w;
    } else {
        int e = (b - LN_BLOCKS) * 256 + threadIdx.x;
        if (e < N_EDGES) atomicAdd(&cnt[rowi[e]], 1);
    }
}

// ---- scan phase A (per-1024-chunk exclusive scan) with fused phase B:
// last finisher block scans the 98 chunk sums in place. cnt keeps LOCAL
// prefixes; global prefix of row i = cnt[i] + bsums[i>>10].
__global__ __launch_bounds__(256) void scan_ab_kernel(int* __restrict__ cnt,
                                                      int* __restrict__ bsums,
                                                      int* __restrict__ done) {
    __shared__ int ts[256];
    __shared__ int amLast;
    int t = threadIdx.x;
    int base = blockIdx.x * 1024 + t * 4;
    int4 v = *(const int4*)(cnt + base);
    int s = v.x + v.y + v.z + v.w;
    ts[t] = s;
    __syncthreads();
    #pragma unroll
    for (int o = 1; o < 256; o <<= 1) {
        int u = 0;
        if (t >= o) u = ts[t - o];
        __syncthreads();
        if (t >= o) ts[t] += u;
        __syncthreads();
    }
    int excl = ts[t] - s;
    int4 w;
    w.x = excl;
    w.y = excl + v.x;
    w.z = excl + v.x + v.y;
    w.w = excl + v.x + v.y + v.z;
    *(int4*)(cnt + base) = w;
    if (t == 255) {
        __hip_atomic_store(&bsums[blockIdx.x], ts[255],
                           __ATOMIC_RELEASE, __HIP_MEMORY_SCOPE_AGENT);
        int prev = __hip_atomic_fetch_add(done, 1,
                                          __ATOMIC_ACQ_REL, __HIP_MEMORY_SCOPE_AGENT);
        amLast = (prev == SCAN_NB - 1);
    }
    __syncthreads();
    if (amLast) {
        __shared__ int ss[128];
        int own = 0;
        if (t < 128) {
            own = (t < SCAN_NB)
                ? __hip_atomic_load(&bsums[t], __ATOMIC_ACQUIRE, __HIP_MEMORY_SCOPE_AGENT)
                : 0;
            ss[t] = own;
        }
        __syncthreads();
        #pragma unroll
        for (int o = 1; o < 128; o <<= 1) {
            int u = 0;
            if (t >= o && t < 128) u = ss[t - o];
            __syncthreads();
            if (t >= o && t < 128) ss[t] += u;
            __syncthreads();
        }
        if (t < SCAN_NB) bsums[t] = ss[t] - own;   // exclusive chunk offsets
    }
}

// Scatter edges into CSR order as interleaved (col, val) 8B pairs.
// cursor holds LOCAL prefixes; global pos = local + bsums[r>>10].
// Afterwards cursor[r] = local inclusive end.
__global__ __launch_bounds__(256) void scatter_kernel(const int* __restrict__ rowi,
                                                      const int* __restrict__ coli,
                                                      const float* __restrict__ vali,
                                                      int* __restrict__ cursor,
                                                      const int* __restrict__ bsums,
                                                      int2* __restrict__ pairs) {
    int e = blockIdx.x * 256 + threadIdx.x;
    if (e >= N_EDGES) return;
    int r = rowi[e];
    int pos = atomicAdd(&cursor[r], 1) + bsums[r >> 10];
    pairs[pos] = make_int2(coli[e], __float_as_int(vali[e]));
}

// ---------------- CSR SpMM over bf16 x: 4 rows/wave (16 lanes x 8 dims) -------
// mode 0: y[row] = bf16(S@x)
// mode 2: out[row] = fp32( S@x + add0[row] + add1[row] ), nontemporal store
__global__ __launch_bounds__(256) void spmm_csr_kernel(const int* __restrict__ row_end,
                                                       const int* __restrict__ bsums,
                                                       const int2* __restrict__ pairs,
                                                       const u32* __restrict__ x,
                                                       u32* __restrict__ y,
                                                       const u32* __restrict__ add0,
                                                       const u32* __restrict__ add1,
                                                       float* __restrict__ out,
                                                       int mode) {
    int tid  = threadIdx.x;
    int wave = tid >> 6;
    int lane = tid & 63;
    int row  = blockIdx.x * 16 + wave * 4 + (lane >> 4);
    int sub  = lane & 15;                          // owns dims [sub*8, sub*8+8)
    int end = row_end[row] + bsums[row >> 10];
    int e   = row ? row_end[row - 1] + bsums[(row - 1) >> 10] : 0;
    const uint4* x4 = (const uint4*)x;             // 16 uint4 per row
    float a0=0,a1=0,a2=0,a3=0,a4=0,a5=0,a6=0,a7=0;
    for (; e + 2 <= end; e += 2) {                 // two gathers in flight
        int2 p0 = pairs[e];
        int2 p1 = pairs[e + 1];
        uint4 g0 = x4[(size_t)p0.x * 16 + sub];
        uint4 g1 = x4[(size_t)p1.x * 16 + sub];
        float v0 = __int_as_float(p0.y);
        float v1 = __int_as_float(p1.y);
        a0 += v0 * bflo(g0.x); a1 += v0 * bfhi(g0.x);
        a2 += v0 * bflo(g0.y); a3 += v0 * bfhi(g0.y);
        a4 += v0 * bflo(g0.z); a5 += v0 * bfhi(g0.z);
        a6 += v0 * bflo(g0.w); a7 += v0 * bfhi(g0.w);
        a0 += v1 * bflo(g1.x); a1 += v1 * bfhi(g1.x);
        a2 += v1 * bflo(g1.y); a3 += v1 * bfhi(g1.y);
        a4 += v1 * bflo(g1.z); a5 += v1 * bfhi(g1.z);
        a6 += v1 * bflo(g1.w); a7 += v1 * bfhi(g1.w);
    }
    if (e < end) {
        int2 p = pairs[e];
        uint4 g = x4[(size_t)p.x * 16 + sub];
        float v = __int_as_float(p.y);
        a0 += v * bflo(g.x); a1 += v * bfhi(g.x);
        a2 += v * bflo(g.y); a3 += v * bfhi(g.y);
        a4 += v * bflo(g.z); a5 += v * bfhi(g.z);
        a6 += v * bflo(g.w); a7 += v * bfhi(g.w);
    }
    size_t oi = (size_t)row * 16 + sub;
    if (mode == 2) {
        uint4 b0 = ((const uint4*)add0)[oi];
        uint4 b1 = ((const uint4*)add1)[oi];
        a0 += bflo(b0.x) + bflo(b1.x); a1 += bfhi(b0.x) + bfhi(b1.x);
        a2 += bflo(b0.y) + bflo(b1.y); a3 += bfhi(b0.y) + bfhi(b1.y);
        a4 += bflo(b0.z) + bflo(b1.z); a5 += bfhi(b0.z) + bfhi(b1.z);
        a6 += bflo(b0.w) + bflo(b1.w); a7 += bfhi(b0.w) + bfhi(b1.w);
        f32x4* o4 = (f32x4*)(out + (size_t)row * LATDIM + sub * 8);
        f32x4 r0 = {a0, a1, a2, a3};
        f32x4 r1 = {a4, a5, a6, a7};
        __builtin_nontemporal_store(r0, o4 + 0);
        __builtin_nontemporal_store(r1, o4 + 1);
    } else {
        uint4 w;
        w.x = pack_bf2(a0, a1);
        w.y = pack_bf2(a2, a3);
        w.z = pack_bf2(a4, a5);
        w.w = pack_bf2(a6, a7);
        ((uint4*)y)[oi] = w;
    }
}

// ---------------- Fallback (atomic, fp32) path -------------------------------
__global__ __launch_bounds__(256) void ln_f32_kernel(const float* __restrict__ in,
                                                     float* __restrict__ out) {
    int tid  = threadIdx.x;
    int wave = tid >> 6;
    int lane = tid & 63;
    int half = lane >> 5;
    int sub  = lane & 31;
    int row  = blockIdx.x * 8 + wave * 2 + half;
    if (row >= N_NODES) return;
    float4 v = ((const float4*)in)[(size_t)row * 32 + sub];
    float s  = v.x + v.y + v.z + v.w;
    float ss = v.x * v.x + v.y * v.y + v.z * v.z + v.w * v.w;
    #pragma unroll
    for (int o = 16; o > 0; o >>= 1) {
        s  += __shfl_xor(s,  o, 64);
        ss += __shfl_xor(ss, o, 64);
    }
    float mu   = s * (1.0f / LATDIM);
    float var  = ss * (1.0f / LATDIM) - mu * mu;
    float rstd = rsqrtf(var + LN_EPS);
    float4 o4;
    o4.x = (v.x - mu) * rstd; o4.y = (v.y - mu) * rstd;
    o4.z = (v.z - mu) * rstd; o4.w = (v.w - mu) * rstd;
    ((float4*)out)[(size_t)row * 32 + sub] = o4;
}

__global__ __launch_bounds__(256) void spmm_atomic_kernel(const int* __restrict__ rowi,
                                                          const int* __restrict__ coli,
                                                          const float* __restrict__ vali,
                                                          const float* __restrict__ x,
                                                          float* __restrict__ y) {
    int t = blockIdx.x * 256 + threadIdx.x;
    int e = t >> 5;
    if (e >= N_EDGES) return;
    int k = t & 31;
    int r = rowi[e];
    int c = coli[e];
    float v = vali[e];
    float4 xv = ((const float4*)(x + (size_t)c * LATDIM))[k];
    float* yp = y + (size_t)r * LATDIM + k * 4;
    atomicAdd(yp + 0, v * xv.x);
    atomicAdd(yp + 1, v * xv.y);
    atomicAdd(yp + 2, v * xv.z);
    atomicAdd(yp + 3, v * xv.w);
}

__global__ __launch_bounds__(256) void addz_kernel(float* __restrict__ acc,
                                                   const float* __restrict__ x,
                                                   float* __restrict__ z,
                                                   int first) {
    size_t i = (size_t)blockIdx.x * 256 + threadIdx.x;
    float4 xv = ((const float4*)x)[i];
    float4* ap = ((float4*)acc) + i;
    if (first) {
        *ap = xv;
    } else {
        float4 a = *ap;
        a.x += xv.x; a.y += xv.y; a.z += xv.z; a.w += xv.w;
        *ap = a;
    }
    if (z) ((float4*)z)[i] = make_float4(0.f, 0.f, 0.f, 0.f);
}

extern "C" void kernel_launch(void* const* d_in, const int* in_sizes, int n_in,
                              void* d_out, int out_size, void* d_ws, size_t ws_size,
                              hipStream_t stream) {
    const float* embeds  = (const float*)d_in[0];
    const int*   adj_row = (const int*)d_in[1];
    const int*   adj_col = (const int*)d_in[2];
    const float* adj_val = (const float*)d_in[3];
    float* out = (float*)d_out;

    // CSR-path layout: two bf16 x buffers + cnt + bsums + done + pairs
    u32*  A16  = (u32*)d_ws;                                    // 25.6 MB
    u32*  B16  = A16 + (size_t)N_NODES * (LATDIM / 2);          // 25.6 MB
    int*  cnt   = (int*)(B16 + (size_t)N_NODES * (LATDIM / 2)); // N_PAD ints
    int*  bsums = cnt + N_PAD;                                  // 128 ints
    int*  done  = bsums + 128;                                  // 32 ints (1 used)
    int2* pairs = (int2*)(done + 32);                           // N_EDGES pairs
    size_t need = (size_t)((char*)(pairs + N_EDGES) - (char*)d_ws);

    const int edgeGrid = (N_EDGES + 255) / 256;       // 2500
    const int rowGrid  = N_NODES / 16;                // 6250 (4 rows/wave)

    if (ws_size >= need) {
        // ---- CSR bf16 path (7 dispatches) ----
        hipMemsetAsync(cnt, 0, (size_t)(N_PAD + 128 + 32) * sizeof(int), stream);
        ln_hist_kernel<<<LN_BLOCKS + HIST_BLOCKS, 256, 0, stream>>>(embeds, A16,
                                                                    adj_row, cnt);
        scan_ab_kernel<<<SCAN_NB, 256, 0, stream>>>(cnt, bsums, done);
        scatter_kernel<<<edgeGrid, 256, 0, stream>>>(adj_row, adj_col, adj_val,
                                                     cnt, bsums, pairs);
        // layer 1: B16 = S@A16 (x1)
        spmm_csr_kernel<<<rowGrid, 256, 0, stream>>>(cnt, bsums, pairs, A16, B16,
                                                     nullptr, nullptr, nullptr, 0);
        // layer 2: A16 = S@B16 (x2, overwrites x0)
        spmm_csr_kernel<<<rowGrid, 256, 0, stream>>>(cnt, bsums, pairs, B16, A16,
                                                     nullptr, nullptr, nullptr, 0);
        // layer 3: out = S@A16 + B16(x1) + A16(x2), fp32 nontemporal
        spmm_csr_kernel<<<rowGrid, 256, 0, stream>>>(cnt, bsums, pairs, A16, nullptr,
                                                     B16, A16, out, 2);
    } else {
        // ---- fallback: fp32 atomic path ----
        float* A = (float*)d_ws;
        float* B = A + (size_t)N_NODES * LATDIM;
        const size_t rowBytes = (size_t)N_NODES * LATDIM * sizeof(float);
        const int spmmGrid = (N_EDGES * 32 + 255) / 256;
        const int addGrid  = (N_NODES * LATDIM / 4 + 255) / 256;
        ln_f32_kernel<<<LN_BLOCKS, 256, 0, stream>>>(embeds, A);
        hipMemsetAsync(B, 0, rowBytes, stream);
        spmm_atomic_kernel<<<spmmGrid, 256, 0, stream>>>(adj_row, adj_col, adj_val, A, B);
        addz_kernel<<<addGrid, 256, 0, stream>>>(out, B, A, 1);
        spmm_atomic_kernel<<<spmmGrid, 256, 0, stream>>>(adj_row, adj_col, adj_val, B, A);
        addz_kernel<<<addGrid, 256, 0, stream>>>(out, A, B, 0);
        spmm_atomic_kernel<<<spmmGrid, 256, 0, stream>>>(adj_row, adj_col, adj_val, A, B);
        addz_kernel<<<addGrid, 256, 0, stream>>>(out, B, nullptr, 0);
    }
}

// Round 8
// 267.672 us; speedup vs baseline: 12.6890x; 1.0430x over previous
//
#include <hip/hip_runtime.h>

#define N_NODES 100000
#define N_EDGES 640000
#define LATDIM  128
#define LN_EPS  1e-5f

typedef unsigned int u32;
typedef float f32x4 __attribute__((ext_vector_type(4)));   // native vector for nt ld/st

// scan geometry: 98 blocks x 1024 elements (256 threads x int4)
#define SCAN_NB   98
#define N_PAD     (SCAN_NB * 1024)   // 100352

#define LN_BLOCKS   (N_NODES / 8)            // 12500
#define HIST_BLOCKS ((N_EDGES + 255) / 256)  // 2500

// ---- bf16 helpers (packed 2x bf16 per u32, element 0 in low half) ----
__device__ __forceinline__ float bflo(u32 u) { return __uint_as_float(u << 16); }
__device__ __forceinline__ float bfhi(u32 u) { return __uint_as_float(u & 0xffff0000u); }
__device__ __forceinline__ u32 pack_bf2(float a, float b) {
    u32 ua = __float_as_uint(a), ub = __float_as_uint(b);
    ua = (ua + 0x7fffu + ((ua >> 16) & 1u)) >> 16;          // RNE
    ub = (ub + 0x7fffu + ((ub >> 16) & 1u)) >> 16;
    return ua | (ub << 16);
}

// ---- 4B edge record: col in bits[16:0], val as 15-bit fixed point in [31:17] --
__device__ __forceinline__ u32 pack_edge(int col, float val) {
    u32 q = (u32)fminf(val * 32768.0f + 0.5f, 32767.0f);
    return (u32)col | (q << 17);
}
__device__ __forceinline__ int   edge_col(u32 r) { return (int)(r & 0x1FFFFu); }
__device__ __forceinline__ float edge_val(u32 r) { return (float)(r >> 17) * (1.0f / 32768.0f); }

// ------------- fused LayerNorm(->bf16) + row histogram (disjoint blocks) ------
__global__ __launch_bounds__(256) void ln_hist_kernel(const float* __restrict__ in,
                                                      u32* __restrict__ out,
                                                      const int* __restrict__ rowi,
                                                      int* __restrict__ cnt) {
    int b = blockIdx.x;
    if (b < LN_BLOCKS) {
        int tid  = threadIdx.x;
        int wave = tid >> 6;
        int lane = tid & 63;
        int half = lane >> 5;
        int sub  = lane & 31;
        int row  = b * 8 + wave * 2 + half;
        f32x4 v = __builtin_nontemporal_load(((const f32x4*)in) + (size_t)row * 32 + sub);
        float s  = v.x + v.y + v.z + v.w;
        float ss = v.x * v.x + v.y * v.y + v.z * v.z + v.w * v.w;
        #pragma unroll
        for (int o = 16; o > 0; o >>= 1) {
            s  += __shfl_xor(s,  o, 64);
            ss += __shfl_xor(ss, o, 64);
        }
        float mu   = s * (1.0f / LATDIM);
        float var  = ss * (1.0f / LATDIM) - mu * mu;
        float rstd = rsqrtf(var + LN_EPS);
        uint2 w;
        w.x = pack_bf2((v.x - mu) * rstd, (v.y - mu) * rstd);
        w.y = pack_bf2((v.z - mu) * rstd, (v.w - mu) * rstd);
        ((uint2*)out)[(size_t)row * 32 + sub] = w;
    } else {
        int e = (b - LN_BLOCKS) * 256 + threadIdx.x;
        if (e < N_EDGES) atomicAdd(&cnt[rowi[e]], 1);
    }
}

// ---- scan phase A (per-1024-chunk exclusive scan) with fused phase B:
// last finisher block scans the 98 chunk sums in place. cnt keeps LOCAL
// prefixes; global prefix of row i = cnt[i] + bsums[i>>10].
__global__ __launch_bounds__(256) void scan_ab_kernel(int* __restrict__ cnt,
                                                      int* __restrict__ bsums,
                                                      int* __restrict__ done) {
    __shared__ int ts[256];
    __shared__ int amLast;
    int t = threadIdx.x;
    int base = blockIdx.x * 1024 + t * 4;
    int4 v = *(const int4*)(cnt + base);
    int s = v.x + v.y + v.z + v.w;
    ts[t] = s;
    __syncthreads();
    #pragma unroll
    for (int o = 1; o < 256; o <<= 1) {
        int u = 0;
        if (t >= o) u = ts[t - o];
        __syncthreads();
        if (t >= o) ts[t] += u;
        __syncthreads();
    }
    int excl = ts[t] - s;
    int4 w;
    w.x = excl;
    w.y = excl + v.x;
    w.z = excl + v.x + v.y;
    w.w = excl + v.x + v.y + v.z;
    *(int4*)(cnt + base) = w;
    if (t == 255) {
        __hip_atomic_store(&bsums[blockIdx.x], ts[255],
                           __ATOMIC_RELEASE, __HIP_MEMORY_SCOPE_AGENT);
        int prev = __hip_atomic_fetch_add(done, 1,
                                          __ATOMIC_ACQ_REL, __HIP_MEMORY_SCOPE_AGENT);
        amLast = (prev == SCAN_NB - 1);
    }
    __syncthreads();
    if (amLast) {
        __shared__ int ss[128];
        int own = 0;
        if (t < 128) {
            own = (t < SCAN_NB)
                ? __hip_atomic_load(&bsums[t], __ATOMIC_ACQUIRE, __HIP_MEMORY_SCOPE_AGENT)
                : 0;
            ss[t] = own;
        }
        __syncthreads();
        #pragma unroll
        for (int o = 1; o < 128; o <<= 1) {
            int u = 0;
            if (t >= o && t < 128) u = ss[t - o];
            __syncthreads();
            if (t >= o && t < 128) ss[t] += u;
            __syncthreads();
        }
        if (t < SCAN_NB) bsums[t] = ss[t] - own;   // exclusive chunk offsets
    }
}

// Scatter edges into CSR order as packed 4B records.
// cursor holds LOCAL prefixes; global pos = local + bsums[r>>10].
__global__ __launch_bounds__(256) void scatter_kernel(const int* __restrict__ rowi,
                                                      const int* __restrict__ coli,
                                                      const float* __restrict__ vali,
                                                      int* __restrict__ cursor,
                                                      const int* __restrict__ bsums,
                                                      u32* __restrict__ recs) {
    int e = blockIdx.x * 256 + threadIdx.x;
    if (e >= N_EDGES) return;
    int r = rowi[e];
    int pos = atomicAdd(&cursor[r], 1) + bsums[r >> 10];
    recs[pos] = pack_edge(coli[e], vali[e]);
}

// ---------------- CSR SpMM over bf16 x: 4 rows/wave (16 lanes x 8 dims) -------
// mode 0: y[row] = bf16(S@x)
// mode 2: out[row] = fp32( S@x + add0[row] + add1[row] ), nontemporal store
__global__ __launch_bounds__(256) void spmm_csr_kernel(const int* __restrict__ row_end,
                                                       const int* __restrict__ bsums,
                                                       const u32* __restrict__ recs,
                                                       const u32* __restrict__ x,
                                                       u32* __restrict__ y,
                                                       const u32* __restrict__ add0,
                                                       const u32* __restrict__ add1,
                                                       float* __restrict__ out,
                                                       int mode) {
    int tid  = threadIdx.x;
    int wave = tid >> 6;
    int lane = tid & 63;
    int row  = blockIdx.x * 16 + wave * 4 + (lane >> 4);
    int sub  = lane & 15;                          // owns dims [sub*8, sub*8+8)
    int end = row_end[row] + bsums[row >> 10];
    int e   = row ? row_end[row - 1] + bsums[(row - 1) >> 10] : 0;
    const uint4* x4 = (const uint4*)x;             // 16 uint4 per row
    float a0=0,a1=0,a2=0,a3=0,a4=0,a5=0,a6=0,a7=0;
    for (; e + 4 <= end; e += 4) {                 // four gathers in flight
        u32 r0 = recs[e], r1 = recs[e+1], r2 = recs[e+2], r3 = recs[e+3];
        uint4 g0 = x4[(size_t)edge_col(r0) * 16 + sub];
        uint4 g1 = x4[(size_t)edge_col(r1) * 16 + sub];
        uint4 g2 = x4[(size_t)edge_col(r2) * 16 + sub];
        uint4 g3 = x4[(size_t)edge_col(r3) * 16 + sub];
        float v0 = edge_val(r0), v1 = edge_val(r1);
        float v2 = edge_val(r2), v3 = edge_val(r3);
        a0 += v0 * bflo(g0.x); a1 += v0 * bfhi(g0.x);
        a2 += v0 * bflo(g0.y); a3 += v0 * bfhi(g0.y);
        a4 += v0 * bflo(g0.z); a5 += v0 * bfhi(g0.z);
        a6 += v0 * bflo(g0.w); a7 += v0 * bfhi(g0.w);
        a0 += v1 * bflo(g1.x); a1 += v1 * bfhi(g1.x);
        a2 += v1 * bflo(g1.y); a3 += v1 * bfhi(g1.y);
        a4 += v1 * bflo(g1.z); a5 += v1 * bfhi(g1.z);
        a6 += v1 * bflo(g1.w); a7 += v1 * bfhi(g1.w);
        a0 += v2 * bflo(g2.x); a1 += v2 * bfhi(g2.x);
        a2 += v2 * bflo(g2.y); a3 += v2 * bfhi(g2.y);
        a4 += v2 * bflo(g2.z); a5 += v2 * bfhi(g2.z);
        a6 += v2 * bflo(g2.w); a7 += v2 * bfhi(g2.w);
        a0 += v3 * bflo(g3.x); a1 += v3 * bfhi(g3.x);
        a2 += v3 * bflo(g3.y); a3 += v3 * bfhi(g3.y);
        a4 += v3 * bflo(g3.z); a5 += v3 * bfhi(g3.z);
        a6 += v3 * bflo(g3.w); a7 += v3 * bfhi(g3.w);
    }
    for (; e < end; ++e) {
        u32 r = recs[e];
        uint4 g = x4[(size_t)edge_col(r) * 16 + sub];
        float v = edge_val(r);
        a0 += v * bflo(g.x); a1 += v * bfhi(g.x);
        a2 += v * bflo(g.y); a3 += v * bfhi(g.y);
        a4 += v * bflo(g.z); a5 += v * bfhi(g.z);
        a6 += v * bflo(g.w); a7 += v * bfhi(g.w);
    }
    size_t oi = (size_t)row * 16 + sub;
    if (mode == 2) {
        uint4 b0 = ((const uint4*)add0)[oi];
        uint4 b1 = ((const uint4*)add1)[oi];
        a0 += bflo(b0.x) + bflo(b1.x); a1 += bfhi(b0.x) + bfhi(b1.x);
        a2 += bflo(b0.y) + bflo(b1.y); a3 += bfhi(b0.y) + bfhi(b1.y);
        a4 += bflo(b0.z) + bflo(b1.z); a5 += bfhi(b0.z) + bfhi(b1.z);
        a6 += bflo(b0.w) + bflo(b1.w); a7 += bfhi(b0.w) + bfhi(b1.w);
        f32x4* o4 = (f32x4*)(out + (size_t)row * LATDIM + sub * 8);
        f32x4 q0 = {a0, a1, a2, a3};
        f32x4 q1 = {a4, a5, a6, a7};
        __builtin_nontemporal_store(q0, o4 + 0);
        __builtin_nontemporal_store(q1, o4 + 1);
    } else {
        uint4 w;
        w.x = pack_bf2(a0, a1);
        w.y = pack_bf2(a2, a3);
        w.z = pack_bf2(a4, a5);
        w.w = pack_bf2(a6, a7);
        ((uint4*)y)[oi] = w;
    }
}

// ---------------- Fallback (atomic, fp32) path -------------------------------
__global__ __launch_bounds__(256) void ln_f32_kernel(const float* __restrict__ in,
                                                     float* __restrict__ out) {
    int tid  = threadIdx.x;
    int wave = tid >> 6;
    int lane = tid & 63;
    int half = lane >> 5;
    int sub  = lane & 31;
    int row  = blockIdx.x * 8 + wave * 2 + half;
    if (row >= N_NODES) return;
    float4 v = ((const float4*)in)[(size_t)row * 32 + sub];
    float s  = v.x + v.y + v.z + v.w;
    float ss = v.x * v.x + v.y * v.y + v.z * v.z + v.w * v.w;
    #pragma unroll
    for (int o = 16; o > 0; o >>= 1) {
        s  += __shfl_xor(s,  o, 64);
        ss += __shfl_xor(ss, o, 64);
    }
    float mu   = s * (1.0f / LATDIM);
    float var  = ss * (1.0f / LATDIM) - mu * mu;
    float rstd = rsqrtf(var + LN_EPS);
    float4 o4;
    o4.x = (v.x - mu) * rstd; o4.y = (v.y - mu) * rstd;
    o4.z = (v.z - mu) * rstd; o4.w = (v.w - mu) * rstd;
    ((float4*)out)[(size_t)row * 32 + sub] = o4;
}

__global__ __launch_bounds__(256) void spmm_atomic_kernel(const int* __restrict__ rowi,
                                                          const int* __restrict__ coli,
                                                          const float* __restrict__ vali,
                                                          const float* __restrict__ x,
                                                          float* __restrict__ y) {
    int t = blockIdx.x * 256 + threadIdx.x;
    int e = t >> 5;
    if (e >= N_EDGES) return;
    int k = t & 31;
    int r = rowi[e];
    int c = coli[e];
    float v = vali[e];
    float4 xv = ((const float4*)(x + (size_t)c * LATDIM))[k];
    float* yp = y + (size_t)r * LATDIM + k * 4;
    atomicAdd(yp + 0, v * xv.x);
    atomicAdd(yp + 1, v * xv.y);
    atomicAdd(yp + 2, v * xv.z);
    atomicAdd(yp + 3, v * xv.w);
}

__global__ __launch_bounds__(256) void addz_kernel(float* __restrict__ acc,
                                                   const float* __restrict__ x,
                                                   float* __restrict__ z,
                                                   int first) {
    size_t i = (size_t)blockIdx.x * 256 + threadIdx.x;
    float4 xv = ((const float4*)x)[i];
    float4* ap = ((float4*)acc) + i;
    if (first) {
        *ap = xv;
    } else {
        float4 a = *ap;
        a.x += xv.x; a.y += xv.y; a.z += xv.z; a.w += xv.w;
        *ap = a;
    }
    if (z) ((float4*)z)[i] = make_float4(0.f, 0.f, 0.f, 0.f);
}

extern "C" void kernel_launch(void* const* d_in, const int* in_sizes, int n_in,
                              void* d_out, int out_size, void* d_ws, size_t ws_size,
                              hipStream_t stream) {
    const float* embeds  = (const float*)d_in[0];
    const int*   adj_row = (const int*)d_in[1];
    const int*   adj_col = (const int*)d_in[2];
    const float* adj_val = (const float*)d_in[3];
    float* out = (float*)d_out;

    // CSR-path layout: two bf16 x buffers + cnt + bsums + done + recs
    u32*  A16  = (u32*)d_ws;                                    // 25.6 MB
    u32*  B16  = A16 + (size_t)N_NODES * (LATDIM / 2);          // 25.6 MB
    int*  cnt   = (int*)(B16 + (size_t)N_NODES * (LATDIM / 2)); // N_PAD ints
    int*  bsums = cnt + N_PAD;                                  // 128 ints
    int*  done  = bsums + 128;                                  // 32 ints (1 used)
    u32*  recs  = (u32*)(done + 32);                            // N_EDGES 4B records
    size_t need = (size_t)((char*)(recs + N_EDGES) - (char*)d_ws);

    const int edgeGrid = (N_EDGES + 255) / 256;       // 2500
    const int rowGrid  = N_NODES / 16;                // 6250 (4 rows/wave)

    if (ws_size >= need) {
        // ---- CSR bf16 path (7 dispatches) ----
        hipMemsetAsync(cnt, 0, (size_t)(N_PAD + 128 + 32) * sizeof(int), stream);
        ln_hist_kernel<<<LN_BLOCKS + HIST_BLOCKS, 256, 0, stream>>>(embeds, A16,
                                                                    adj_row, cnt);
        scan_ab_kernel<<<SCAN_NB, 256, 0, stream>>>(cnt, bsums, done);
        scatter_kernel<<<edgeGrid, 256, 0, stream>>>(adj_row, adj_col, adj_val,
                                                     cnt, bsums, recs);
        // layer 1: B16 = S@A16 (x1)
        spmm_csr_kernel<<<rowGrid, 256, 0, stream>>>(cnt, bsums, recs, A16, B16,
                                                     nullptr, nullptr, nullptr, 0);
        // layer 2: A16 = S@B16 (x2, overwrites x0)
        spmm_csr_kernel<<<rowGrid, 256, 0, stream>>>(cnt, bsums, recs, B16, A16,
                                                     nullptr, nullptr, nullptr, 0);
        // layer 3: out = S@A16 + B16(x1) + A16(x2), fp32 nontemporal
        spmm_csr_kernel<<<rowGrid, 256, 0, stream>>>(cnt, bsums, recs, A16, nullptr,
                                                     B16, A16, out, 2);
    } else {
        // ---- fallback: fp32 atomic path ----
        float* A = (float*)d_ws;
        float* B = A + (size_t)N_NODES * LATDIM;
        const size_t rowBytes = (size_t)N_NODES * LATDIM * sizeof(float);
        const int spmmGrid = (N_EDGES * 32 + 255) / 256;
        const int addGrid  = (N_NODES * LATDIM / 4 + 255) / 256;
        ln_f32_kernel<<<LN_BLOCKS, 256, 0, stream>>>(embeds, A);
        hipMemsetAsync(B, 0, rowBytes, stream);
        spmm_atomic_kernel<<<spmmGrid, 256, 0, stream>>>(adj_row, adj_col, adj_val, A, B);
        addz_kernel<<<addGrid, 256, 0, stream>>>(out, B, A, 1);
        spmm_atomic_kernel<<<spmmGrid, 256, 0, stream>>>(adj_row, adj_col, adj_val, B, A);
        addz_kernel<<<addGrid, 256, 0, stream>>>(out, A, B, 0);
        spmm_atomic_kernel<<<spmmGrid, 256, 0, stream>>>(adj_row, adj_col, adj_val, A, B);
        addz_kernel<<<addGrid, 256, 0, stream>>>(out, B, nullptr, 0);
    }
}

// Round 10
// 256.985 us; speedup vs baseline: 13.2167x; 1.0416x over previous
//
#include <hip/hip_runtime.h>

#define N_NODES 100000
#define N_EDGES 640000
#define LATDIM  128
#define LN_EPS  1e-5f

typedef unsigned int u32;
typedef float f32x4 __attribute__((ext_vector_type(4)));   // native vector for nt ld/st

// scan geometry: 98 chunks x 1024 rows (256 threads x int4)
#define SCAN_NB   98
#define N_PAD     (SCAN_NB * 1024)   // 100352

#define LN_BLOCKS   (N_NODES / 8)            // 12500
#define HIST_BLOCKS ((N_EDGES + 255) / 256)  // 2500

// bucket_append geometry: 7 edges/thread, 1792 edges/block
#define APP_K      7
#define APP_EDGES  (256 * APP_K)                          // 1792
#define APP_NB     ((N_EDGES + APP_EDGES - 1) / APP_EDGES) // 358

// ---- bf16 helpers (packed 2x bf16 per u32, element 0 in low half) ----
__device__ __forceinline__ float bflo(u32 u) { return __uint_as_float(u << 16); }
__device__ __forceinline__ float bfhi(u32 u) { return __uint_as_float(u & 0xffff0000u); }
__device__ __forceinline__ u32 pack_bf2(float a, float b) {
    u32 ua = __float_as_uint(a), ub = __float_as_uint(b);
    ua = (ua + 0x7fffu + ((ua >> 16) & 1u)) >> 16;          // RNE
    ub = (ub + 0x7fffu + ((ub >> 16) & 1u)) >> 16;
    return ua | (ub << 16);
}

// ---- 4B edge record: col in bits[16:0], val as 15-bit fixed point in [31:17] --
__device__ __forceinline__ u32 pack_edge(int col, float val) {
    u32 q = (u32)fminf(val * 32768.0f + 0.5f, 32767.0f);
    return (u32)col | (q << 17);
}
__device__ __forceinline__ int   edge_col(u32 r) { return (int)(r & 0x1FFFFu); }
__device__ __forceinline__ float edge_val(u32 r) { return (float)(r >> 17) * (1.0f / 32768.0f); }

// ------------- fused LayerNorm(->bf16) + row histogram (disjoint blocks) ------
__global__ __launch_bounds__(256) void ln_hist_kernel(const float* __restrict__ in,
                                                      u32* __restrict__ out,
                                                      const int* __restrict__ rowi,
                                                      int* __restrict__ cnt) {
    int b = blockIdx.x;
    if (b < LN_BLOCKS) {
        int tid  = threadIdx.x;
        int wave = tid >> 6;
        int lane = tid & 63;
        int half = lane >> 5;
        int sub  = lane & 31;
        int row  = b * 8 + wave * 2 + half;
        f32x4 v = __builtin_nontemporal_load(((const f32x4*)in) + (size_t)row * 32 + sub);
        float s  = v.x + v.y + v.z + v.w;
        float ss = v.x * v.x + v.y * v.y + v.z * v.z + v.w * v.w;
        #pragma unroll
        for (int o = 16; o > 0; o >>= 1) {
            s  += __shfl_xor(s,  o, 64);
            ss += __shfl_xor(ss, o, 64);
        }
        float mu   = s * (1.0f / LATDIM);
        float var  = ss * (1.0f / LATDIM) - mu * mu;
        float rstd = rsqrtf(var + LN_EPS);
        uint2 w;
        w.x = pack_bf2((v.x - mu) * rstd, (v.y - mu) * rstd);
        w.y = pack_bf2((v.z - mu) * rstd, (v.w - mu) * rstd);
        ((uint2*)out)[(size_t)row * 32 + sub] = w;
    } else {
        int e = (b - LN_BLOCKS) * 256 + threadIdx.x;
        if (e < N_EDGES) atomicAdd(&cnt[rowi[e]], 1);
    }
}

// ---- scan phase A: per-1024-chunk exclusive scan; chunk sum -> csums.
// cnt keeps LOCAL exclusive prefixes. (Cross-kernel handoff only — no
// intra-kernel cross-workgroup ordering, per G16.)
__global__ __launch_bounds__(256) void scan_a_kernel(int* __restrict__ cnt,
                                                     int* __restrict__ csums) {
    __shared__ int ts[256];
    int t = threadIdx.x;
    int base = blockIdx.x * 1024 + t * 4;
    int4 v = *(const int4*)(cnt + base);
    int s = v.x + v.y + v.z + v.w;
    ts[t] = s;
    __syncthreads();
    #pragma unroll
    for (int o = 1; o < 256; o <<= 1) {
        int u = 0;
        if (t >= o) u = ts[t - o];
        __syncthreads();
        if (t >= o) ts[t] += u;
        __syncthreads();
    }
    int excl = ts[t] - s;
    int4 w;
    w.x = excl;
    w.y = excl + v.x;
    w.z = excl + v.x + v.y;
    w.w = excl + v.x + v.y + v.z;
    *(int4*)(cnt + base) = w;
    if (t == 255) csums[blockIdx.x] = ts[255];
}

// ---- scan phase B: 1 block; exclusive scan of 98 chunk sums.
// bsums[b] = global start of chunk b; bsums[98] = N_EDGES sentinel;
// gcur[b] = bsums[b] (cursor for bucket_append).
__global__ __launch_bounds__(128) void scan_b_kernel(const int* __restrict__ csums,
                                                     int* __restrict__ bsums,
                                                     int* __restrict__ gcur) {
    __shared__ int ss[128];
    int t = threadIdx.x;
    int own = (t < SCAN_NB) ? csums[t] : 0;
    ss[t] = own;
    __syncthreads();
    #pragma unroll
    for (int o = 1; o < 128; o <<= 1) {
        int u = 0;
        if (t >= o) u = ss[t - o];
        __syncthreads();
        if (t >= o) ss[t] += u;
        __syncthreads();
    }
    if (t < SCAN_NB) {
        int off = ss[t] - own;                 // exclusive chunk offset
        bsums[t] = off;
        gcur[t]  = off;
    }
    if (t == SCAN_NB) bsums[SCAN_NB] = N_EDGES;
}

// ---- phase 1: bucket append. Edges -> chunk-bucketed staging (8B records),
// block-aggregated reservations so writes per bucket are contiguous per block.
// staging record: x = (rowLocal<<17)|col, y = val bits.
__global__ __launch_bounds__(256) void bucket_append_kernel(const int* __restrict__ rowi,
                                                            const int* __restrict__ coli,
                                                            const float* __restrict__ vali,
                                                            int* __restrict__ gcur,
                                                            uint2* __restrict__ staging) {
    __shared__ int hist[SCAN_NB];
    __shared__ int base[SCAN_NB];
    int t = threadIdx.x;
    if (t < SCAN_NB) hist[t] = 0;
    __syncthreads();
    int e0 = blockIdx.x * APP_EDGES;
    int r[APP_K]; int c[APP_K]; float v[APP_K]; int bk[APP_K];
    #pragma unroll
    for (int k = 0; k < APP_K; ++k) {
        int e = e0 + k * 256 + t;
        if (e < N_EDGES) {
            r[k] = rowi[e]; c[k] = coli[e]; v[k] = vali[e];
            bk[k] = r[k] >> 10;
            atomicAdd(&hist[bk[k]], 1);
        } else {
            bk[k] = -1;
        }
    }
    __syncthreads();
    if (t < SCAN_NB) {
        int h = hist[t];
        base[t] = h ? atomicAdd(&gcur[t], h) : 0;   // order-free reservation
        hist[t] = 0;                               // reuse as local cursor
    }
    __syncthreads();
    #pragma unroll
    for (int k = 0; k < APP_K; ++k) {
        if (bk[k] >= 0) {
            int idx = atomicAdd(&hist[bk[k]], 1);
            staging[base[bk[k]] + idx] =
                make_uint2(((u32)(r[k] & 1023) << 17) | (u32)c[k],
                           __float_as_uint(v[k]));
        }
    }
}

// ---- phase 2: fine scatter within a chunk. Block b scatters its chunk's
// staging records into final CSR order (26KB L2-resident window).
__global__ __launch_bounds__(256) void fine_scatter_kernel(const int* __restrict__ cnt,
                                                           const int* __restrict__ bsums,
                                                           const uint2* __restrict__ staging,
                                                           u32* __restrict__ recs) {
    __shared__ int cur[1024];
    int b = blockIdx.x, t = threadIdx.x;
    *(int4*)&cur[t * 4] = *(const int4*)&cnt[b * 1024 + t * 4];
    __syncthreads();
    int gbase = bsums[b];
    int n = bsums[b + 1] - gbase;
    for (int i = t; i < n; i += 256) {
        uint2 s = staging[gbase + i];
        int rowLocal = (int)(s.x >> 17);
        int col = (int)(s.x & 0x1FFFFu);
        int pos = gbase + atomicAdd(&cur[rowLocal], 1);
        recs[pos] = pack_edge(col, __uint_as_float(s.y));
    }
}

// ---------------- CSR SpMM over bf16 x: 4 rows/wave (16 lanes x 8 dims) -------
// cnt holds local EXCLUSIVE prefixes; start = cnt[row]+bsums[row>>10],
// end = cnt[row+1]+bsums[(row+1)>>10] (valid at row 99999 via zero-padded tail).
// mode 0: y[row] = bf16(S@x)
// mode 2: out[row] = fp32( S@x + add0[row] + add1[row] ), nontemporal store
__global__ __launch_bounds__(256) void spmm_csr_kernel(const int* __restrict__ cnt,
                                                       const int* __restrict__ bsums,
                                                       const u32* __restrict__ recs,
                                                       const u32* __restrict__ x,
                                                       u32* __restrict__ y,
                                                       const u32* __restrict__ add0,
                                                       const u32* __restrict__ add1,
                                                       float* __restrict__ out,
                                                       int mode) {
    int tid  = threadIdx.x;
    int wave = tid >> 6;
    int lane = tid & 63;
    int row  = blockIdx.x * 16 + wave * 4 + (lane >> 4);
    int sub  = lane & 15;                          // owns dims [sub*8, sub*8+8)
    int e   = cnt[row]     + bsums[row >> 10];
    int end = cnt[row + 1] + bsums[(row + 1) >> 10];
    const uint4* x4 = (const uint4*)x;             // 16 uint4 per row
    float a0=0,a1=0,a2=0,a3=0,a4=0,a5=0,a6=0,a7=0;
    for (; e + 4 <= end; e += 4) {                 // four gathers in flight
        u32 r0 = recs[e], r1 = recs[e+1], r2 = recs[e+2], r3 = recs[e+3];
        uint4 g0 = x4[(size_t)edge_col(r0) * 16 + sub];
        uint4 g1 = x4[(size_t)edge_col(r1) * 16 + sub];
        uint4 g2 = x4[(size_t)edge_col(r2) * 16 + sub];
        uint4 g3 = x4[(size_t)edge_col(r3) * 16 + sub];
        float v0 = edge_val(r0), v1 = edge_val(r1);
        float v2 = edge_val(r2), v3 = edge_val(r3);
        a0 += v0 * bflo(g0.x); a1 += v0 * bfhi(g0.x);
        a2 += v0 * bflo(g0.y); a3 += v0 * bfhi(g0.y);
        a4 += v0 * bflo(g0.z); a5 += v0 * bfhi(g0.z);
        a6 += v0 * bflo(g0.w); a7 += v0 * bfhi(g0.w);
        a0 += v1 * bflo(g1.x); a1 += v1 * bfhi(g1.x);
        a2 += v1 * bflo(g1.y); a3 += v1 * bfhi(g1.y);
        a4 += v1 * bflo(g1.z); a5 += v1 * bfhi(g1.z);
        a6 += v1 * bflo(g1.w); a7 += v1 * bfhi(g1.w);
        a0 += v2 * bflo(g2.x); a1 += v2 * bfhi(g2.x);
        a2 += v2 * bflo(g2.y); a3 += v2 * bfhi(g2.y);
        a4 += v2 * bflo(g2.z); a5 += v2 * bfhi(g2.z);
        a6 += v2 * bflo(g2.w); a7 += v2 * bfhi(g2.w);
        a0 += v3 * bflo(g3.x); a1 += v3 * bfhi(g3.x);
        a2 += v3 * bflo(g3.y); a3 += v3 * bfhi(g3.y);
        a4 += v3 * bflo(g3.z); a5 += v3 * bfhi(g3.z);
        a6 += v3 * bflo(g3.w); a7 += v3 * bfhi(g3.w);
    }
    for (; e < end; ++e) {
        u32 r = recs[e];
        uint4 g = x4[(size_t)edge_col(r) * 16 + sub];
        float v = edge_val(r);
        a0 += v * bflo(g.x); a1 += v * bfhi(g.x);
        a2 += v * bflo(g.y); a3 += v * bfhi(g.y);
        a4 += v * bflo(g.z); a5 += v * bfhi(g.z);
        a6 += v * bflo(g.w); a7 += v * bfhi(g.w);
    }
    size_t oi = (size_t)row * 16 + sub;
    if (mode == 2) {
        uint4 b0 = ((const uint4*)add0)[oi];
        uint4 b1 = ((const uint4*)add1)[oi];
        a0 += bflo(b0.x) + bflo(b1.x); a1 += bfhi(b0.x) + bfhi(b1.x);
        a2 += bflo(b0.y) + bflo(b1.y); a3 += bfhi(b0.y) + bfhi(b1.y);
        a4 += bflo(b0.z) + bflo(b1.z); a5 += bfhi(b0.z) + bfhi(b1.z);
        a6 += bflo(b0.w) + bflo(b1.w); a7 += bfhi(b0.w) + bfhi(b1.w);
        f32x4* o4 = (f32x4*)(out + (size_t)row * LATDIM + sub * 8);
        f32x4 q0 = {a0, a1, a2, a3};
        f32x4 q1 = {a4, a5, a6, a7};
        __builtin_nontemporal_store(q0, o4 + 0);
        __builtin_nontemporal_store(q1, o4 + 1);
    } else {
        uint4 w;
        w.x = pack_bf2(a0, a1);
        w.y = pack_bf2(a2, a3);
        w.z = pack_bf2(a4, a5);
        w.w = pack_bf2(a6, a7);
        ((uint4*)y)[oi] = w;
    }
}

// ---------------- Fallback (atomic, fp32) path -------------------------------
__global__ __launch_bounds__(256) void ln_f32_kernel(const float* __restrict__ in,
                                                     float* __restrict__ out) {
    int tid  = threadIdx.x;
    int wave = tid >> 6;
    int lane = tid & 63;
    int half = lane >> 5;
    int sub  = lane & 31;
    int row  = blockIdx.x * 8 + wave * 2 + half;
    if (row >= N_NODES) return;
    float4 v = ((const float4*)in)[(size_t)row * 32 + sub];
    float s  = v.x + v.y + v.z + v.w;
    float ss = v.x * v.x + v.y * v.y + v.z * v.z + v.w * v.w;
    #pragma unroll
    for (int o = 16; o > 0; o >>= 1) {
        s  += __shfl_xor(s,  o, 64);
        ss += __shfl_xor(ss, o, 64);
    }
    float mu   = s * (1.0f / LATDIM);
    float var  = ss * (1.0f / LATDIM) - mu * mu;
    float rstd = rsqrtf(var + LN_EPS);
    float4 o4;
    o4.x = (v.x - mu) * rstd; o4.y = (v.y - mu) * rstd;
    o4.z = (v.z - mu) * rstd; o4.w = (v.w - mu) * rstd;
    ((float4*)out)[(size_t)row * 32 + sub] = o4;
}

__global__ __launch_bounds__(256) void spmm_atomic_kernel(const int* __restrict__ rowi,
                                                          const int* __restrict__ coli,
                                                          const float* __restrict__ vali,
                                                          const float* __restrict__ x,
                                                          float* __restrict__ y) {
    int t = blockIdx.x * 256 + threadIdx.x;
    int e = t >> 5;
    if (e >= N_EDGES) return;
    int k = t & 31;
    int r = rowi[e];
    int c = coli[e];
    float v = vali[e];
    float4 xv = ((const float4*)(x + (size_t)c * LATDIM))[k];
    float* yp = y + (size_t)r * LATDIM + k * 4;
    atomicAdd(yp + 0, v * xv.x);
    atomicAdd(yp + 1, v * xv.y);
    atomicAdd(yp + 2, v * xv.z);
    atomicAdd(yp + 3, v * xv.w);
}

__global__ __launch_bounds__(256) void addz_kernel(float* __restrict__ acc,
                                                   const float* __restrict__ x,
                                                   float* __restrict__ z,
                                                   int first) {
    size_t i = (size_t)blockIdx.x * 256 + threadIdx.x;
    float4 xv = ((const float4*)x)[i];
    float4* ap = ((float4*)acc) + i;
    if (first) {
        *ap = xv;
    } else {
        float4 a = *ap;
        a.x += xv.x; a.y += xv.y; a.z += xv.z; a.w += xv.w;
        *ap = a;
    }
    if (z) ((float4*)z)[i] = make_float4(0.f, 0.f, 0.f, 0.f);
}

extern "C" void kernel_launch(void* const* d_in, const int* in_sizes, int n_in,
                              void* d_out, int out_size, void* d_ws, size_t ws_size,
                              hipStream_t stream) {
    const float* embeds  = (const float*)d_in[0];
    const int*   adj_row = (const int*)d_in[1];
    const int*   adj_col = (const int*)d_in[2];
    const float* adj_val = (const float*)d_in[3];
    float* out = (float*)d_out;

    // CSR-path layout
    u32*   A16   = (u32*)d_ws;                                    // 25.6 MB
    u32*   B16   = A16 + (size_t)N_NODES * (LATDIM / 2);          // 25.6 MB
    int*   cnt   = (int*)(B16 + (size_t)N_NODES * (LATDIM / 2));  // N_PAD ints
    int*   csums = cnt + N_PAD;                                   // 128 ints (98 used)
    int*   bsums = csums + 128;                                   // 128 ints (99 used)
    int*   gcur  = bsums + 128;                                   // 128 ints (98 used)
    uint2* staging = (uint2*)(gcur + 128);                        // N_EDGES 8B recs
    u32*   recs  = (u32*)(staging + N_EDGES);                     // N_EDGES 4B recs
    size_t need  = (size_t)((char*)(recs + N_EDGES) - (char*)d_ws);

    const int rowGrid = N_NODES / 16;                 // 6250 (4 rows/wave)

    if (ws_size >= need) {
        // ---- CSR bf16 path (9 dispatches incl. memset) ----
        hipMemsetAsync(cnt, 0, (size_t)N_PAD * sizeof(int), stream);
        ln_hist_kernel<<<LN_BLOCKS + HIST_BLOCKS, 256, 0, stream>>>(embeds, A16,
                                                                    adj_row, cnt);
        scan_a_kernel<<<SCAN_NB, 256, 0, stream>>>(cnt, csums);
        scan_b_kernel<<<1, 128, 0, stream>>>(csums, bsums, gcur);
        bucket_append_kernel<<<APP_NB, 256, 0, stream>>>(adj_row, adj_col, adj_val,
                                                         gcur, staging);
        fine_scatter_kernel<<<SCAN_NB, 256, 0, stream>>>(cnt, bsums, staging, recs);
        // layer 1: B16 = S@A16 (x1)
        spmm_csr_kernel<<<rowGrid, 256, 0, stream>>>(cnt, bsums, recs, A16, B16,
                                                     nullptr, nullptr, nullptr, 0);
        // layer 2: A16 = S@B16 (x2, overwrites x0)
        spmm_csr_kernel<<<rowGrid, 256, 0, stream>>>(cnt, bsums, recs, B16, A16,
                                                     nullptr, nullptr, nullptr, 0);
        // layer 3: out = S@A16 + B16(x1) + A16(x2), fp32 nontemporal
        spmm_csr_kernel<<<rowGrid, 256, 0, stream>>>(cnt, bsums, recs, A16, nullptr,
                                                     B16, A16, out, 2);
    } else {
        // ---- fallback: fp32 atomic path ----
        float* A = (float*)d_ws;
        float* B = A + (size_t)N_NODES * LATDIM;
        const size_t rowBytes = (size_t)N_NODES * LATDIM * sizeof(float);
        const int spmmGrid = (N_EDGES * 32 + 255) / 256;
        const int addGrid  = (N_NODES * LATDIM / 4 + 255) / 256;
        ln_f32_kernel<<<LN_BLOCKS, 256, 0, stream>>>(embeds, A);
        hipMemsetAsync(B, 0, rowBytes, stream);
        spmm_atomic_kernel<<<spmmGrid, 256, 0, stream>>>(adj_row, adj_col, adj_val, A, B);
        addz_kernel<<<addGrid, 256, 0, stream>>>(out, B, A, 1);
        spmm_atomic_kernel<<<spmmGrid, 256, 0, stream>>>(adj_row, adj_col, adj_val, B, A);
        addz_kernel<<<addGrid, 256, 0, stream>>>(out, A, B, 0);
        spmm_atomic_kernel<<<spmmGrid, 256, 0, stream>>>(adj_row, adj_col, adj_val, A, B);
        addz_kernel<<<addGrid, 256, 0, stream>>>(out, B, nullptr, 0);
    }
}